// Round 13
// baseline (897.422 us; speedup 1.0000x reference)
//
#include <hip/hip_runtime.h>

#define H 128
#define F_IN 16
#define BNEPS 1e-5f

typedef __attribute__((ext_vector_type(8))) short short8;
typedef __attribute__((ext_vector_type(4))) float f32x4;

// f32 -> bf16 round-to-nearest-even
__device__ __forceinline__ unsigned short f2bf(float f)
{
    unsigned u = __builtin_bit_cast(unsigned, f);
    u += 0x7FFFu + ((u >> 16) & 1u);
    return (unsigned short)(u >> 16);
}

// ---------------------------------------------------------------------------
// Stage a 64x128 bf16 tile (rows r0..) into swizzled LDS (pure copy).
// element (row,k) -> ushort idx row*128 + (k ^ ((row&7)<<3))
__device__ __forceinline__ void stage_copy(const unsigned short* __restrict__ src,
                                           unsigned short* sA, int r0, int M, int t)
{
#pragma unroll
    for (int i = 0; i < 4; ++i) {
        int cid  = t + 256 * i;
        int row  = cid >> 4;
        int ck   = cid & 15;
        int grow = r0 + row;
        short8 v = (short8)0;
        if (grow < M)
            v = *(const short8*)(src + (size_t)grow * H + ck * 8);
        *(short8*)(sA + (row << 7) + ((ck ^ (row & 7)) << 3)) = v;
    }
}

// Gather variant: tile row i holds src[idx[p0+i]].
__device__ __forceinline__ void stage_copy_gather(const unsigned short* __restrict__ src,
                                                  const int* __restrict__ idx,
                                                  unsigned short* sA, int p0, int M, int t)
{
#pragma unroll
    for (int i = 0; i < 4; ++i) {
        int cid = t + 256 * i;
        int row = cid >> 4;
        int ck  = cid & 15;
        int p   = p0 + row;
        short8 v = (short8)0;
        if (p < M)
            v = *(const short8*)(src + (size_t)idx[p] * H + ck * 8);
        *(short8*)(sA + (row << 7) + ((ck ^ (row & 7)) << 3)) = v;
    }
}

// value = aggsum[row][k] / max(cnt[row],1) -> bf16 (aggsum f32, cnt int)
__device__ __forceinline__ void stage_agg_bf16(const float* __restrict__ aggsum,
                                               const int* __restrict__ cnt,
                                               unsigned short* sA, int r0, int M, int t)
{
#pragma unroll
    for (int i = 0; i < 4; ++i) {
        int cid  = t + 256 * i;
        int row  = cid >> 4;
        int ck   = cid & 15;
        int grow = r0 + row;
        short8 ph = (short8)0;
        if (grow < M) {
            const float4* q = (const float4*)(aggsum + (size_t)grow * H + ck * 8);
            float4 a = q[0], b = q[1];
            int c = cnt[grow];
            float inv = 1.f / (float)(c > 1 ? c : 1);
            float xs[8] = {a.x * inv, a.y * inv, a.z * inv, a.w * inv,
                           b.x * inv, b.y * inv, b.z * inv, b.w * inv};
#pragma unroll
            for (int j = 0; j < 8; ++j) ph[j] = (short)f2bf(xs[j]);
        }
        *(short8*)(sA + (row << 7) + ((ck ^ (row & 7)) << 3)) = ph;
    }
}

// ---------------------------------------------------------------------------
// Per-layer prep: s,t for h and e BN, plus effective biases.
// sbuf: s_h[0:128] t_h[128] s_e[256] t_e[384] beff[512] b1eff[640] b2eff[768]
__global__ __launch_bounds__(128) void prep_kernel(const float* __restrict__ Sh,
                                                   const float* __restrict__ Se,
                                                   const float* __restrict__ gh,
                                                   const float* __restrict__ bh,
                                                   const float* __restrict__ ge,
                                                   const float* __restrict__ beC,
                                                   float invN, float invE,
                                                   const float* __restrict__ W1,
                                                   const float* __restrict__ W2,
                                                   const float* __restrict__ W3,
                                                   const float* __restrict__ U1,
                                                   const float* __restrict__ V1,
                                                   const float* __restrict__ be,
                                                   const float* __restrict__ b1,
                                                   const float* __restrict__ b2,
                                                   float* __restrict__ sbuf)
{
    __shared__ float th[128], te[128];
    int j = threadIdx.x;
    float s = 1.f, t = 0.f;
    if (Sh) {
        float mean = Sh[j] * invN;
        float var  = Sh[H + j] * invN - mean * mean;
        s = rsqrtf(var + BNEPS) * gh[j];
        t = bh[j] - mean * s;
    }
    sbuf[j] = s; sbuf[128 + j] = t; th[j] = t;
    s = 1.f; t = 0.f;
    if (Se) {
        float mean = Se[j] * invE;
        float var  = Se[H + j] * invE - mean * mean;
        s = rsqrtf(var + BNEPS) * ge[j];
        t = beC[j] - mean * s;
    }
    sbuf[256 + j] = s; sbuf[384 + j] = t; te[j] = t;
    __syncthreads();
    float a1 = be[j], a2 = b1[j], a3 = b2[j];
    for (int k = 0; k < H; ++k) {
        float thk = th[k], tek = te[k];
        a1 += thk * (W1[k * H + j] + W2[k * H + j]) + tek * W3[k * H + j];
        a2 += thk * U1[k * H + j];
        a3 += thk * V1[k * H + j];
    }
    sbuf[512 + j] = a1;
    sbuf[640 + j] = a2;
    sbuf[768 + j] = a3;
}

// Per-layer scaled bf16 weight fragments. 7 mats [W1',W2',W3',U1',U2,V1',V2].
// Per matrix: 2048 short8; entry idx=((jbB*4+s)*2+c)*64+lane holds
// scale[kk]*W[kk=32s+8g+j][jbB*32+16c+c0].
__global__ __launch_bounds__(256) void wfrag_kernel(const float* __restrict__ edge_w_l,
                                                    const float* __restrict__ n1_w_l,
                                                    const float* __restrict__ n2_w_l,
                                                    const float* __restrict__ sbuf,
                                                    short8* __restrict__ out)
{
    int m = blockIdx.x;
    const float* W;
    const float* scale;   // nullptr = identity
    const float* s_h = sbuf, *s_e = sbuf + 256;
    switch (m) {
        case 0: W = edge_w_l;             scale = s_h; break;
        case 1: W = edge_w_l + H * H;     scale = s_h; break;
        case 2: W = edge_w_l + 2 * H * H; scale = s_e; break;
        case 3: W = n1_w_l;               scale = s_h; break;
        case 4: W = n1_w_l + H * H;       scale = nullptr; break;
        case 5: W = n2_w_l;               scale = s_h; break;
        default: W = n2_w_l + H * H;      scale = nullptr; break;
    }
    short8* oh = out + (size_t)m * 2048;
    for (int e = threadIdx.x; e < 2048; e += 256) {
        int jbB = e >> 9, s = (e >> 7) & 3, c = (e >> 6) & 1, lane = e & 63;
        int g = lane >> 4, c0 = lane & 15;
        short8 hi;
#pragma unroll
        for (int j = 0; j < 8; ++j) {
            int kk = 32 * s + 8 * g + j;
            float v = W[(size_t)kk * H + jbB * 32 + 16 * c + c0];
            if (scale) v *= scale[kk];
            hi[j] = (short)f2bf(v);
        }
        oh[e] = hi;
    }
}

// Load precomputed bf16 fragments: 8 coalesced 16B loads.
__device__ __forceinline__ void load_wfrag(const short8* __restrict__ Wp, int jbB,
                                           int lane, short8 wf[4][2])
{
#pragma unroll
    for (int s = 0; s < 4; ++s)
#pragma unroll
        for (int c = 0; c < 2; ++c)
            wf[s][c] = Wp[((jbB * 4 + s) * 2 + c) * 64 + lane];
}

// acc += sA(64x128 bf16, swizzled) @ Wf(128x32 bf16)
__device__ __forceinline__ void mfma_gemm(const unsigned short* sA, const short8 wf[4][2],
                                          f32x4 acc[4][2], int lane)
{
    const int g = lane >> 4, r = lane & 15;
#pragma unroll
    for (int s = 0; s < 4; ++s) {
        short8 a4[4];
#pragma unroll
        for (int fr = 0; fr < 4; ++fr) {
            int row = 16 * fr + r;
            int ck  = (4 * s + g) ^ (row & 7);
            a4[fr] = *(const short8*)(sA + (row << 7) + (ck << 3));
        }
#pragma unroll
        for (int fr = 0; fr < 4; ++fr)
#pragma unroll
            for (int c = 0; c < 2; ++c)
                acc[fr][c] = __builtin_amdgcn_mfma_f32_16x16x32_bf16(a4[fr], wf[s][c],
                                                                     acc[fr][c], 0, 0, 0);
    }
}

__device__ __forceinline__ void zero_acc(f32x4 acc[4][2])
{
#pragma unroll
    for (int fr = 0; fr < 4; ++fr)
#pragma unroll
        for (int c = 0; c < 2; ++c) {
            acc[fr][c][0] = 0.f; acc[fr][c][1] = 0.f;
            acc[fr][c][2] = 0.f; acc[fr][c][3] = 0.f;
        }
}

// ---------------------------------------------------------------------------
// One-time sort machinery (edge_index is layer-invariant)
__global__ __launch_bounds__(256) void hist_kernel(const int* __restrict__ col,
                                                   int* __restrict__ cnt, int E)
{
    int e = blockIdx.x * 256 + threadIdx.x;
    if (e < E) atomicAdd(&cnt[col[e]], 1);
}

__global__ __launch_bounds__(1024) void scan_kernel(const int* __restrict__ cnt,
                                                    int* __restrict__ offs, int Nn)
{
    __shared__ int ls[1024];
    int t = threadIdx.x;
    int per = (Nn + 1023) / 1024;
    int base = t * per;
    int s = 0;
    for (int k = 0; k < per; ++k) {
        int i = base + k;
        if (i < Nn) s += cnt[i];
    }
    ls[t] = s;
    __syncthreads();
    for (int d = 1; d < 1024; d <<= 1) {
        int u = (t >= d) ? ls[t - d] : 0;
        __syncthreads();
        ls[t] += u;
        __syncthreads();
    }
    int run = ls[t] - s;
    for (int k = 0; k < per; ++k) {
        int i = base + k;
        if (i < Nn) {
            offs[i] = run;
            run += cnt[i];
        }
    }
}

__global__ __launch_bounds__(256) void scatter_kernel(const int* __restrict__ row,
                                                      const int* __restrict__ col,
                                                      const int* __restrict__ offs,
                                                      int* __restrict__ tmpc,
                                                      int* __restrict__ sortedIds,
                                                      int* __restrict__ rowS,
                                                      int* __restrict__ colS, int E)
{
    int e = blockIdx.x * 256 + threadIdx.x;
    if (e < E) {
        int c = col[e];
        int p = offs[c] + atomicAdd(&tmpc[c], 1);
        sortedIds[p] = e;
        rowS[p] = row[e];
        colS[p] = c;
    }
}

// ---------------------------------------------------------------------------
// Encoder: out(bf16) = relu(X[M,16] @ W[16,128] + b)
__global__ __launch_bounds__(256) void enc_kernel(const float* __restrict__ X,
                                                  const float* __restrict__ W,
                                                  const float* __restrict__ bias,
                                                  unsigned short* __restrict__ out, int M)
{
    __shared__ float sW[F_IN * H];
    __shared__ float sb[H];
    int t = threadIdx.x;
    reinterpret_cast<float4*>(sW)[t]       = reinterpret_cast<const float4*>(W)[t];
    reinterpret_cast<float4*>(sW)[t + 256] = reinterpret_cast<const float4*>(W)[t + 256];
    if (t < H) sb[t] = bias[t];
    __syncthreads();
    int row = blockIdx.x * 2 + (t >> 7);
    if (row >= M) return;
    int j = t & 127;
    float acc = sb[j];
#pragma unroll
    for (int k = 0; k < F_IN; ++k)
        acc += X[(size_t)row * F_IN + k] * sW[k * H + j];
    out[(size_t)row * H + j] = f2bf(fmaxf(acc, 0.f));
}

// Gather-encoder: out[p](bf16) = relu(X[sortedIds[p],16] @ W + b)
__global__ __launch_bounds__(256) void enc_gather_kernel(const float* __restrict__ X,
                                                         const int* __restrict__ sortedIds,
                                                         const float* __restrict__ W,
                                                         const float* __restrict__ bias,
                                                         unsigned short* __restrict__ out,
                                                         int M)
{
    __shared__ float sW[F_IN * H];
    __shared__ float sb[H];
    int t = threadIdx.x;
    reinterpret_cast<float4*>(sW)[t]       = reinterpret_cast<const float4*>(W)[t];
    reinterpret_cast<float4*>(sW)[t + 256] = reinterpret_cast<const float4*>(W)[t + 256];
    if (t < H) sb[t] = bias[t];
    __syncthreads();
    int p = blockIdx.x * 2 + (t >> 7);
    if (p >= M) return;
    int src = sortedIds[p];
    int j = t & 127;
    float acc = sb[j];
#pragma unroll
    for (int k = 0; k < F_IN; ++k)
        acc += X[(size_t)src * F_IN + k] * sW[k * H + j];
    out[(size_t)p * H + j] = f2bf(fmaxf(acc, 0.f));
}

// ---------------------------------------------------------------------------
// B precompute: B(f32) = h(bf16) @ W2'  (BN folded into W2', bias in beff)
__global__ __launch_bounds__(256, 4) void bk_kernel(const unsigned short* __restrict__ hb,
                                                    const short8* __restrict__ W2p,
                                                    float* __restrict__ Bout, int M)
{
    __shared__ __align__(16) unsigned short sA[64 * 128];
    const int t = threadIdx.x, lane = t & 63, w = t >> 6, jb = 32 * w;
    const int r0 = blockIdx.x * 64;
    stage_copy(hb, sA, r0, M, t);
    const int g = lane >> 4, c0 = lane & 15;
    short8 wf[4][2];
    load_wfrag(W2p, w, lane, wf);
    f32x4 acc[4][2];
    zero_acc(acc);
    __syncthreads();
    mfma_gemm(sA, wf, acc, lane);
#pragma unroll
    for (int fr = 0; fr < 4; ++fr)
#pragma unroll
        for (int c = 0; c < 2; ++c) {
            int j = jb + 16 * c + c0;
#pragma unroll
            for (int r = 0; r < 4; ++r) {
                int row = r0 + 16 * fr + 4 * g + r;
                if (row < M) Bout[(size_t)row * H + j] = acc[fr][c][r];
            }
        }
}

// ---------------------------------------------------------------------------
// Fused edge kernel (bf16 e in col-sorted layout, BN folded into weights):
//   e'[p] = relu(e[p]@W3' + h[rowS]@W1' + B[colS] + beff)
//   m     = relu(e'@U2 + h[rowS]@U1' + b1eff)
//   aggsum[col] += segment-reduced m ; fused e'-stats
__global__ __launch_bounds__(256, 4) void edge_kernel(unsigned short* eb,
                                                      const int* __restrict__ rowS,
                                                      const int* __restrict__ colS,
                                                      const unsigned short* __restrict__ hb,
                                                      const float* __restrict__ Bsrc,
                                                      const short8* __restrict__ wfr,
                                                      const float* __restrict__ sbuf,
                                                      float* __restrict__ aggsum, int E,
                                                      float* __restrict__ eStats)
{
    __shared__ __align__(16) unsigned char smem[64 * 128 * 4 + 256];
    unsigned short* sE  = (unsigned short*)smem;          // 16 KB  e (bf16)
    unsigned short* sHt = sE + 64 * 128;                  // 16 KB  h[row] (bf16)
    float*          mbuf = (float*)smem;                  // 32 KB overlay (post-GEMM2)
    int*            scol = (int*)(smem + 64 * 128 * 4);   // 256 B

    const int t = threadIdx.x, lane = t & 63, w = t >> 6, jb = 32 * w;
    const int e0 = blockIdx.x * 64;
    const int g = lane >> 4, c0 = lane & 15;
    const float* beff  = sbuf + 512;
    const float* b1eff = sbuf + 640;

    if (t < 64) scol[t] = colS[(e0 + t < E) ? (e0 + t) : (E - 1)];

    // per-lane col indices + early B prefetch
    int cidx[4][4];
#pragma unroll
    for (int fr = 0; fr < 4; ++fr)
#pragma unroll
        for (int r = 0; r < 4; ++r) {
            int p  = e0 + 16 * fr + 4 * g + r;
            int pc = (p < E) ? p : (E - 1);
            cidx[fr][r] = colS[pc];
        }
    float bPre[4][2][4];
#pragma unroll
    for (int fr = 0; fr < 4; ++fr)
#pragma unroll
        for (int c = 0; c < 2; ++c)
#pragma unroll
            for (int r = 0; r < 4; ++r)
                bPre[fr][c][r] = Bsrc[(size_t)cidx[fr][r] * H + jb + 16 * c + c0];

    // stage e tile + gathered h[row] tile (pure bf16 copies)
    stage_copy(eb, sE, e0, E, t);
    stage_copy_gather(hb, rowS, sHt, e0, E, t);

    short8 wf[4][2];
    f32x4 acc[4][2];
    zero_acc(acc);
    load_wfrag(wfr + 2 * 2048, w, lane, wf);   // W3'
    __syncthreads();
    mfma_gemm(sE, wf, acc, lane);
    load_wfrag(wfr + 0 * 2048, w, lane, wf);   // W1'
    mfma_gemm(sHt, wf, acc, lane);
    __syncthreads();   // all reads of sE done -> safe to overwrite with e'

    // epilogue 1: e' = relu(acc + B[col] + beff) -> bf16 global + back to sE
    float s1[2] = {0.f, 0.f}, s2[2] = {0.f, 0.f};
#pragma unroll
    for (int fr = 0; fr < 4; ++fr)
#pragma unroll
        for (int c = 0; c < 2; ++c) {
            int j = jb + 16 * c + c0;
            float bej = beff[j];
#pragma unroll
            for (int r = 0; r < 4; ++r) {
                int Rl = 16 * fr + 4 * g + r;
                int p  = e0 + Rl;
                float v = acc[fr][c][r] + bPre[fr][c][r] + bej;
                v = fmaxf(v, 0.f);
                unsigned short vb = f2bf(v);
                if (p < E) {
                    eb[(size_t)p * H + j] = vb;
                    s1[c] += v;
                    s2[c] += v * v;
                }
                sE[(Rl << 7) + (j ^ ((Rl & 7) << 3))] = vb;
            }
        }
    __syncthreads();

    // GEMM2: m = e'@U2 + h[rowS]@U1'
    zero_acc(acc);
    load_wfrag(wfr + 4 * 2048, w, lane, wf);   // U2
    mfma_gemm(sE, wf, acc, lane);
    load_wfrag(wfr + 3 * 2048, w, lane, wf);   // U1'
    mfma_gemm(sHt, wf, acc, lane);
    __syncthreads();   // all GEMM2 LDS reads done -> mbuf overlay safe

    // epilogue 2: m -> mbuf (swizzled)
#pragma unroll
    for (int fr = 0; fr < 4; ++fr)
#pragma unroll
        for (int c = 0; c < 2; ++c) {
            int j = jb + 16 * c + c0;
            float b1j = b1eff[j];
#pragma unroll
            for (int r = 0; r < 4; ++r) {
                int Rl = 16 * fr + 4 * g + r;
                float v = fmaxf(acc[fr][c][r] + b1j, 0.f);
                mbuf[(Rl << 7) + (j ^ (((Rl >> 2) & 3) << 3))] = v;
            }
        }
    __syncthreads();

    // segmented reduction: thread j walks 64 sorted rows, 1 atomic per segment
    if (t < 128) {
        int j = t;
        float run = 0.f;
        int cur = scol[0];
        for (int row = 0; row < 64; ++row) {
            int cc = scol[row];
            float v = mbuf[(row << 7) + (j ^ (((row >> 2) & 3) << 3))];
            if (cc != cur) {
                atomicAdd(&aggsum[(size_t)cur * H + j], run);
                run = 0.f;
                cur = cc;
            }
            if (e0 + row < E) run += v;
        }
        atomicAdd(&aggsum[(size_t)cur * H + j], run);
    }

    // fused e'-stats
#pragma unroll
    for (int c = 0; c < 2; ++c) {
        float a = s1[c], b = s2[c];
        a += __shfl_xor(a, 16); a += __shfl_xor(a, 32);
        b += __shfl_xor(b, 16); b += __shfl_xor(b, 32);
        if (g == 0) {
            int j = jb + 16 * c + c0;
            atomicAdd(&eStats[j], a);
            atomicAdd(&eStats[H + j], b);
        }
    }
}

// ---------------------------------------------------------------------------
// Node update (in place, bf16 h): h = relu(h@V1' + agg@V2 + b2eff); fused stats
__global__ __launch_bounds__(256, 4) void node_kernel(unsigned short* hb,
                                                      const float* __restrict__ aggsum,
                                                      const int* __restrict__ cnt,
                                                      const short8* __restrict__ wfr,
                                                      const float* __restrict__ sbuf,
                                                      int M,
                                                      float* __restrict__ hStats)
{
    __shared__ __align__(16) unsigned short sA[64 * 128];
    const int t = threadIdx.x, lane = t & 63, w = t >> 6, jb = 32 * w;
    const int r0 = blockIdx.x * 64;
    const float* b2eff = sbuf + 768;
    stage_copy(hb, sA, r0, M, t);
    short8 wf[4][2];
    load_wfrag(wfr + 5 * 2048, w, lane, wf);   // V1'
    f32x4 acc[4][2];
    zero_acc(acc);
    __syncthreads();
    mfma_gemm(sA, wf, acc, lane);
    __syncthreads();   // h-tile reads done
    stage_agg_bf16(aggsum, cnt, sA, r0, M, t);
    load_wfrag(wfr + 6 * 2048, w, lane, wf);   // V2
    __syncthreads();
    mfma_gemm(sA, wf, acc, lane);
    const int g = lane >> 4, c0 = lane & 15;
    float s1[2] = {0.f, 0.f}, s2[2] = {0.f, 0.f};
#pragma unroll
    for (int fr = 0; fr < 4; ++fr)
#pragma unroll
        for (int c = 0; c < 2; ++c) {
            int j = jb + 16 * c + c0;
            float bj = b2eff[j];
#pragma unroll
            for (int r = 0; r < 4; ++r) {
                int row = r0 + 16 * fr + 4 * g + r;
                if (row < M) {
                    float v = fmaxf(acc[fr][c][r] + bj, 0.f);
                    hb[(size_t)row * H + j] = f2bf(v);
                    s1[c] += v;
                    s2[c] += v * v;
                }
            }
        }
#pragma unroll
    for (int c = 0; c < 2; ++c) {
        float a = s1[c], b = s2[c];
        a += __shfl_xor(a, 16); a += __shfl_xor(a, 32);
        b += __shfl_xor(b, 16); b += __shfl_xor(b, 32);
        if (g == 0) {
            int j = jb + 16 * c + c0;
            atomicAdd(&hStats[j], a);
            atomicAdd(&hStats[H + j], b);
        }
    }
}

// ---------------------------------------------------------------------------
// Final readout: out = [mean(h) | mean(e)] @ reg_w + reg_b
__global__ __launch_bounds__(256) void final_kernel(const float* __restrict__ hsum,
                                                    const float* __restrict__ esum,
                                                    const float* __restrict__ reg_w,
                                                    const float* __restrict__ reg_b,
                                                    float* __restrict__ out,
                                                    float invN, float invE)
{
    __shared__ float red[256];
    int t = threadIdx.x;
    float v = (t < 128) ? hsum[t] * invN * reg_w[t]
                        : esum[t - 128] * invE * reg_w[t];
    red[t] = v;
    __syncthreads();
    for (int s = 128; s > 0; s >>= 1) {
        if (t < s) red[t] += red[t + s];
        __syncthreads();
    }
    if (t == 0) out[0] = red[0] + reg_b[0];
}

// ---------------------------------------------------------------------------
extern "C" void kernel_launch(void* const* d_in, const int* in_sizes, int n_in,
                              void* d_out, int out_size, void* d_ws, size_t ws_size,
                              hipStream_t stream)
{
    const float* x          = (const float*)d_in[0];
    const int*   edge_index = (const int*)  d_in[1];
    const float* edge_attr  = (const float*)d_in[2];
    const float* enc_node_w = (const float*)d_in[3];
    const float* enc_node_b = (const float*)d_in[4];
    const float* enc_edge_w = (const float*)d_in[5];
    const float* enc_edge_b = (const float*)d_in[6];
    const float* edge_w     = (const float*)d_in[7];
    const float* edge_b     = (const float*)d_in[8];
    const float* n1_w       = (const float*)d_in[9];
    const float* n1_b       = (const float*)d_in[10];
    const float* n2_w       = (const float*)d_in[11];
    const float* n2_b       = (const float*)d_in[12];
    const float* bn_node_g  = (const float*)d_in[13];
    const float* bn_node_b  = (const float*)d_in[14];
    const float* bn_edge_g  = (const float*)d_in[15];
    const float* bn_edge_b  = (const float*)d_in[16];
    const float* reg_w      = (const float*)d_in[17];
    const float* reg_b      = (const float*)d_in[18];

    const int N = in_sizes[0] / F_IN;
    const int E = in_sizes[1] / 2;
    const size_t NH = (size_t)N * H;
    const size_t EH = (size_t)E * H;

    float* ws     = (float*)d_ws;
    float* Bbuf   = ws;                 // [N,128] f32
    float* aggsum = Bbuf + NH;          // [N,128] f32
    float* statsA = aggsum + NH;        // 512
    float* statsB = statsA + 512;       // 512
    float* sbuf   = statsB + 512;       // 896 (s/t/beff/b1eff/b2eff)
    short8* wfr   = (short8*)(sbuf + 896);          // 7*2048 short8 = 224 KB
    unsigned short* hbuf = (unsigned short*)(wfr + 7 * 2048);  // [N,128] bf16
    unsigned short* ebuf = hbuf + NH;                          // [E,128] bf16 (col-sorted)
    int*   cnt_i  = (int*)(ebuf + EH);      // [N]
    int*   tmpc   = cnt_i + N;              // [N]
    int*   offs   = tmpc + N;               // [N+1]
    int*   sortedIds = offs + N + 1;        // [E]
    int*   rowS   = sortedIds + E;          // [E]
    int*   colS   = rowS + E;               // [E]

    const int* row_idx = edge_index;
    const int* col_idx = edge_index + E;
    const float invN = 1.f / (float)N;
    const float invE = 1.f / (float)E;

    // one-time: sort edges by col, build permuted index arrays
    (void)hipMemsetAsync(cnt_i, 0, (size_t)2 * N * sizeof(int), stream);
    hist_kernel<<<(E + 255) / 256, 256, 0, stream>>>(col_idx, cnt_i, E);
    scan_kernel<<<1, 1024, 0, stream>>>(cnt_i, offs, N);
    scatter_kernel<<<(E + 255) / 256, 256, 0, stream>>>(row_idx, col_idx, offs, tmpc,
                                                        sortedIds, rowS, colS, E);

    enc_kernel<<<(N + 1) / 2, 256, 0, stream>>>(x, enc_node_w, enc_node_b, hbuf, N);
    enc_gather_kernel<<<(E + 1) / 2, 256, 0, stream>>>(edge_attr, sortedIds,
                                                       enc_edge_w, enc_edge_b, ebuf, E);

    const int nodeBlocks = (N + 63) / 64;
    const int edgeBlocks = (E + 63) / 64;

    for (int i = 0; i < 3; ++i) {
        float*       Scur  = (i & 1) ? statsB : statsA;
        const float* Sprev = (i == 0) ? nullptr : ((i & 1) ? statsA : statsB);
        const float* We = edge_w + (size_t)i * 384 * H;
        const float* Wu = n1_w + (size_t)i * 256 * H;
        const float* Wv = n2_w + (size_t)i * 256 * H;
        prep_kernel<<<1, 128, 0, stream>>>(
            Sprev, Sprev ? Sprev + 256 : nullptr,
            bn_node_g, bn_node_b, bn_edge_g, bn_edge_b, invN, invE,
            We, We + H * H, We + 2 * H * H, Wu, Wv,
            edge_b + i * H, n1_b + i * H, n2_b + i * H, sbuf);
        wfrag_kernel<<<7, 256, 0, stream>>>(We, Wu, Wv, sbuf, wfr);
        (void)hipMemsetAsync(aggsum, 0, NH * sizeof(float), stream);
        (void)hipMemsetAsync(Scur, 0, 512 * sizeof(float), stream);
        bk_kernel<<<nodeBlocks, 256, 0, stream>>>(hbuf, wfr + 1 * 2048, Bbuf, N);
        edge_kernel<<<edgeBlocks, 256, 0, stream>>>(
            ebuf, rowS, colS, hbuf, Bbuf, wfr, sbuf, aggsum, E, Scur + 256);
        node_kernel<<<nodeBlocks, 256, 0, stream>>>(
            hbuf, aggsum, cnt_i, wfr, sbuf, N, Scur);
    }
    // i=2 wrote statsA
    final_kernel<<<1, 256, 0, stream>>>(statsA, statsA + 256, reg_w, reg_b,
                                        (float*)d_out, invN, invE);
}

// Round 14
// 896.112 us; speedup vs baseline: 1.0015x; 1.0015x over previous
//
#include <hip/hip_runtime.h>

#define H 128
#define F_IN 16
#define BNEPS 1e-5f

typedef __attribute__((ext_vector_type(8))) short short8;
typedef __attribute__((ext_vector_type(4))) float f32x4;

// f32 -> bf16 round-to-nearest-even
__device__ __forceinline__ unsigned short f2bf(float f)
{
    unsigned u = __builtin_bit_cast(unsigned, f);
    u += 0x7FFFu + ((u >> 16) & 1u);
    return (unsigned short)(u >> 16);
}
__device__ __forceinline__ float bf2f(unsigned short h)
{
    return __builtin_bit_cast(float, (unsigned)h << 16);
}

// ---------------------------------------------------------------------------
// Stage a 64x128 bf16 tile (rows r0..) into swizzled LDS (pure copy).
// element (row,k) -> ushort idx row*128 + (k ^ ((row&7)<<3))
__device__ __forceinline__ void stage_copy(const unsigned short* __restrict__ src,
                                           unsigned short* sA, int r0, int M, int t)
{
#pragma unroll
    for (int i = 0; i < 4; ++i) {
        int cid  = t + 256 * i;
        int row  = cid >> 4;
        int ck   = cid & 15;
        int grow = r0 + row;
        short8 v = (short8)0;
        if (grow < M)
            v = *(const short8*)(src + (size_t)grow * H + ck * 8);
        *(short8*)(sA + (row << 7) + ((ck ^ (row & 7)) << 3)) = v;
    }
}

// Gather variant: tile row i holds src[idx[p0+i]].
__device__ __forceinline__ void stage_copy_gather(const unsigned short* __restrict__ src,
                                                  const int* __restrict__ idx,
                                                  unsigned short* sA, int p0, int M, int t)
{
#pragma unroll
    for (int i = 0; i < 4; ++i) {
        int cid = t + 256 * i;
        int row = cid >> 4;
        int ck  = cid & 15;
        int p   = p0 + row;
        short8 v = (short8)0;
        if (p < M)
            v = *(const short8*)(src + (size_t)idx[p] * H + ck * 8);
        *(short8*)(sA + (row << 7) + ((ck ^ (row & 7)) << 3)) = v;
    }
}

// value = aggsum[row][k] / max(cnt[row],1) -> bf16 (aggsum f32, cnt int)
__device__ __forceinline__ void stage_agg_bf16(const float* __restrict__ aggsum,
                                               const int* __restrict__ cnt,
                                               unsigned short* sA, int r0, int M, int t)
{
#pragma unroll
    for (int i = 0; i < 4; ++i) {
        int cid  = t + 256 * i;
        int row  = cid >> 4;
        int ck   = cid & 15;
        int grow = r0 + row;
        short8 ph = (short8)0;
        if (grow < M) {
            const float4* q = (const float4*)(aggsum + (size_t)grow * H + ck * 8);
            float4 a = q[0], b = q[1];
            int c = cnt[grow];
            float inv = 1.f / (float)(c > 1 ? c : 1);
            float xs[8] = {a.x * inv, a.y * inv, a.z * inv, a.w * inv,
                           b.x * inv, b.y * inv, b.z * inv, b.w * inv};
#pragma unroll
            for (int j = 0; j < 8; ++j) ph[j] = (short)f2bf(xs[j]);
        }
        *(short8*)(sA + (row << 7) + ((ck ^ (row & 7)) << 3)) = ph;
    }
}

// ---------------------------------------------------------------------------
// Per-layer prep (tiny, no loops): s,t for h and e BN.
// sbuf: s_h[0:128] t_h[128] s_e[256] t_e[384] beff[512] b1eff[640] b2eff[768]
__global__ __launch_bounds__(128) void prep_kernel(const float* __restrict__ Sh,
                                                   const float* __restrict__ Se,
                                                   const float* __restrict__ gh,
                                                   const float* __restrict__ bh,
                                                   const float* __restrict__ ge,
                                                   const float* __restrict__ beC,
                                                   float invN, float invE,
                                                   float* __restrict__ sbuf)
{
    int j = threadIdx.x;
    float s = 1.f, t = 0.f;
    if (Sh) {
        float mean = Sh[j] * invN;
        float var  = Sh[H + j] * invN - mean * mean;
        s = rsqrtf(var + BNEPS) * gh[j];
        t = bh[j] - mean * s;
    }
    sbuf[j] = s; sbuf[128 + j] = t;
    s = 1.f; t = 0.f;
    if (Se) {
        float mean = Se[j] * invE;
        float var  = Se[H + j] * invE - mean * mean;
        s = rsqrtf(var + BNEPS) * ge[j];
        t = beC[j] - mean * s;
    }
    sbuf[256 + j] = s; sbuf[384 + j] = t;
}

// Per-layer scaled bf16 weight fragments + effective biases.
// Blocks 0..6: weight mats [W1',W2',W3',U1',U2,V1',V2] (2048 short8 each;
// entry idx=((jbB*4+s)*2+c)*64+lane holds scale[kk]*W[kk=32s+8g+j][jbB*32+16c+c0]).
// Block 7: beff = be + t_h@(W1+W2) + t_e@W3 ; 8: b1eff = b1 + t_h@U1 ;
// 9: b2eff = b2 + t_h@V1.
__global__ __launch_bounds__(256) void wfrag_kernel(const float* __restrict__ edge_w_l,
                                                    const float* __restrict__ n1_w_l,
                                                    const float* __restrict__ n2_w_l,
                                                    const float* __restrict__ be,
                                                    const float* __restrict__ b1,
                                                    const float* __restrict__ b2,
                                                    float* __restrict__ sbuf,
                                                    short8* __restrict__ out)
{
    int m = blockIdx.x;
    int t = threadIdx.x;
    if (m >= 7) {
        __shared__ float part[256];
        int j = t & 127, half = t >> 7;
        const float* th = sbuf + 128;
        const float* te = sbuf + 384;
        float a = 0.f;
        int k0 = half * 64;
        if (m == 7) {
            for (int k = k0; k < k0 + 64; ++k)
                a += th[k] * (edge_w_l[k * H + j] + edge_w_l[H * H + k * H + j])
                   + te[k] * edge_w_l[2 * H * H + k * H + j];
        } else if (m == 8) {
            for (int k = k0; k < k0 + 64; ++k)
                a += th[k] * n1_w_l[k * H + j];
        } else {
            for (int k = k0; k < k0 + 64; ++k)
                a += th[k] * n2_w_l[k * H + j];
        }
        part[t] = a;
        __syncthreads();
        if (half == 0) {
            float base = (m == 7) ? be[j] : (m == 8) ? b1[j] : b2[j];
            sbuf[512 + (m - 7) * 128 + j] = base + part[j] + part[j + 128];
        }
        return;
    }
    const float* W;
    const float* scale;   // nullptr = identity
    const float* s_h = sbuf, *s_e = sbuf + 256;
    switch (m) {
        case 0: W = edge_w_l;             scale = s_h; break;
        case 1: W = edge_w_l + H * H;     scale = s_h; break;
        case 2: W = edge_w_l + 2 * H * H; scale = s_e; break;
        case 3: W = n1_w_l;               scale = s_h; break;
        case 4: W = n1_w_l + H * H;       scale = nullptr; break;
        case 5: W = n2_w_l;               scale = s_h; break;
        default: W = n2_w_l + H * H;      scale = nullptr; break;
    }
    short8* oh = out + (size_t)m * 2048;
    for (int e = t; e < 2048; e += 256) {
        int jbB = e >> 9, s = (e >> 7) & 3, c = (e >> 6) & 1, lane = e & 63;
        int g = lane >> 4, c0 = lane & 15;
        short8 hi;
#pragma unroll
        for (int j = 0; j < 8; ++j) {
            int kk = 32 * s + 8 * g + j;
            float v = W[(size_t)kk * H + jbB * 32 + 16 * c + c0];
            if (scale) v *= scale[kk];
            hi[j] = (short)f2bf(v);
        }
        oh[e] = hi;
    }
}

// Load precomputed bf16 fragments: 8 coalesced 16B loads.
__device__ __forceinline__ void load_wfrag(const short8* __restrict__ Wp, int jbB,
                                           int lane, short8 wf[4][2])
{
#pragma unroll
    for (int s = 0; s < 4; ++s)
#pragma unroll
        for (int c = 0; c < 2; ++c)
            wf[s][c] = Wp[((jbB * 4 + s) * 2 + c) * 64 + lane];
}

// acc += sA(64x128 bf16, swizzled) @ Wf(128x32 bf16)
__device__ __forceinline__ void mfma_gemm(const unsigned short* sA, const short8 wf[4][2],
                                          f32x4 acc[4][2], int lane)
{
    const int g = lane >> 4, r = lane & 15;
#pragma unroll
    for (int s = 0; s < 4; ++s) {
        short8 a4[4];
#pragma unroll
        for (int fr = 0; fr < 4; ++fr) {
            int row = 16 * fr + r;
            int ck  = (4 * s + g) ^ (row & 7);
            a4[fr] = *(const short8*)(sA + (row << 7) + (ck << 3));
        }
#pragma unroll
        for (int fr = 0; fr < 4; ++fr)
#pragma unroll
            for (int c = 0; c < 2; ++c)
                acc[fr][c] = __builtin_amdgcn_mfma_f32_16x16x32_bf16(a4[fr], wf[s][c],
                                                                     acc[fr][c], 0, 0, 0);
    }
}

__device__ __forceinline__ void zero_acc(f32x4 acc[4][2])
{
#pragma unroll
    for (int fr = 0; fr < 4; ++fr)
#pragma unroll
        for (int c = 0; c < 2; ++c) {
            acc[fr][c][0] = 0.f; acc[fr][c][1] = 0.f;
            acc[fr][c][2] = 0.f; acc[fr][c][3] = 0.f;
        }
}

// ---------------------------------------------------------------------------
// One-time sort machinery (edge_index is layer-invariant)
__global__ __launch_bounds__(256) void hist_kernel(const int* __restrict__ col,
                                                   int* __restrict__ cnt, int E)
{
    int e = blockIdx.x * 256 + threadIdx.x;
    if (e < E) atomicAdd(&cnt[col[e]], 1);
}

__global__ __launch_bounds__(1024) void scan_kernel(const int* __restrict__ cnt,
                                                    int* __restrict__ offs, int Nn)
{
    __shared__ int ls[1024];
    int t = threadIdx.x;
    int per = (Nn + 1023) / 1024;
    int base = t * per;
    int s = 0;
    for (int k = 0; k < per; ++k) {
        int i = base + k;
        if (i < Nn) s += cnt[i];
    }
    ls[t] = s;
    __syncthreads();
    for (int d = 1; d < 1024; d <<= 1) {
        int u = (t >= d) ? ls[t - d] : 0;
        __syncthreads();
        ls[t] += u;
        __syncthreads();
    }
    int run = ls[t] - s;
    for (int k = 0; k < per; ++k) {
        int i = base + k;
        if (i < Nn) {
            offs[i] = run;
            run += cnt[i];
        }
    }
}

__global__ __launch_bounds__(256) void scatter_kernel(const int* __restrict__ row,
                                                      const int* __restrict__ col,
                                                      const int* __restrict__ offs,
                                                      int* __restrict__ tmpc,
                                                      int* __restrict__ sortedIds,
                                                      int* __restrict__ rowS,
                                                      int* __restrict__ colS, int E)
{
    int e = blockIdx.x * 256 + threadIdx.x;
    if (e < E) {
        int c = col[e];
        int p = offs[c] + atomicAdd(&tmpc[c], 1);
        sortedIds[p] = e;
        rowS[p] = row[e];
        colS[p] = c;
    }
}

// ---------------------------------------------------------------------------
// Encoder: out(bf16) = relu(X[M,16] @ W[16,128] + b)
__global__ __launch_bounds__(256) void enc_kernel(const float* __restrict__ X,
                                                  const float* __restrict__ W,
                                                  const float* __restrict__ bias,
                                                  unsigned short* __restrict__ out, int M)
{
    __shared__ float sW[F_IN * H];
    __shared__ float sb[H];
    int t = threadIdx.x;
    reinterpret_cast<float4*>(sW)[t]       = reinterpret_cast<const float4*>(W)[t];
    reinterpret_cast<float4*>(sW)[t + 256] = reinterpret_cast<const float4*>(W)[t + 256];
    if (t < H) sb[t] = bias[t];
    __syncthreads();
    int row = blockIdx.x * 2 + (t >> 7);
    if (row >= M) return;
    int j = t & 127;
    float acc = sb[j];
#pragma unroll
    for (int k = 0; k < F_IN; ++k)
        acc += X[(size_t)row * F_IN + k] * sW[k * H + j];
    out[(size_t)row * H + j] = f2bf(fmaxf(acc, 0.f));
}

// Gather-encoder: out[p](bf16) = relu(X[sortedIds[p],16] @ W + b)
__global__ __launch_bounds__(256) void enc_gather_kernel(const float* __restrict__ X,
                                                         const int* __restrict__ sortedIds,
                                                         const float* __restrict__ W,
                                                         const float* __restrict__ bias,
                                                         unsigned short* __restrict__ out,
                                                         int M)
{
    __shared__ float sW[F_IN * H];
    __shared__ float sb[H];
    int t = threadIdx.x;
    reinterpret_cast<float4*>(sW)[t]       = reinterpret_cast<const float4*>(W)[t];
    reinterpret_cast<float4*>(sW)[t + 256] = reinterpret_cast<const float4*>(W)[t + 256];
    if (t < H) sb[t] = bias[t];
    __syncthreads();
    int p = blockIdx.x * 2 + (t >> 7);
    if (p >= M) return;
    int src = sortedIds[p];
    int j = t & 127;
    float acc = sb[j];
#pragma unroll
    for (int k = 0; k < F_IN; ++k)
        acc += X[(size_t)src * F_IN + k] * sW[k * H + j];
    out[(size_t)p * H + j] = f2bf(fmaxf(acc, 0.f));
}

// ---------------------------------------------------------------------------
// B precompute: B(bf16) = h(bf16) @ W2'  (BN folded into W2')
__global__ __launch_bounds__(256, 8) void bk_kernel(const unsigned short* __restrict__ hb,
                                                    const short8* __restrict__ W2p,
                                                    unsigned short* __restrict__ Bout, int M)
{
    __shared__ __align__(16) unsigned short sA[64 * 128];
    const int t = threadIdx.x, lane = t & 63, w = t >> 6, jb = 32 * w;
    const int r0 = blockIdx.x * 64;
    stage_copy(hb, sA, r0, M, t);
    const int g = lane >> 4, c0 = lane & 15;
    short8 wf[4][2];
    load_wfrag(W2p, w, lane, wf);
    f32x4 acc[4][2];
    zero_acc(acc);
    __syncthreads();
    mfma_gemm(sA, wf, acc, lane);
#pragma unroll
    for (int fr = 0; fr < 4; ++fr)
#pragma unroll
        for (int c = 0; c < 2; ++c) {
            int j = jb + 16 * c + c0;
#pragma unroll
            for (int r = 0; r < 4; ++r) {
                int row = r0 + 16 * fr + 4 * g + r;
                if (row < M) Bout[(size_t)row * H + j] = f2bf(acc[fr][c][r]);
            }
        }
}

// ---------------------------------------------------------------------------
// Fused edge kernel (bf16 e in col-sorted layout, BN folded into weights):
//   e'[p] = relu(e[p]@W3' + h[rowS]@W1' + B[colS] + beff)
//   m     = relu(e'@U2 + h[rowS]@U1' + b1eff)
//   aggsum[col] += segment-reduced m ; fused e'-stats
__global__ __launch_bounds__(256, 4) void edge_kernel(unsigned short* eb,
                                                      const int* __restrict__ rowS,
                                                      const int* __restrict__ colS,
                                                      const unsigned short* __restrict__ hb,
                                                      const unsigned short* __restrict__ Bsrc,
                                                      const short8* __restrict__ wfr,
                                                      const float* __restrict__ sbuf,
                                                      float* __restrict__ aggsum, int E,
                                                      float* __restrict__ eStats)
{
    __shared__ __align__(16) unsigned char smem[64 * 128 * 4 + 256];
    unsigned short* sE  = (unsigned short*)smem;          // 16 KB  e (bf16)
    unsigned short* sHt = sE + 64 * 128;                  // 16 KB  h[row] (bf16)
    float*          mbuf = (float*)smem;                  // 32 KB overlay (post-GEMM2)
    int*            scol = (int*)(smem + 64 * 128 * 4);   // 256 B

    const int t = threadIdx.x, lane = t & 63, w = t >> 6, jb = 32 * w;
    const int e0 = blockIdx.x * 64;
    const int g = lane >> 4, c0 = lane & 15;
    const float* beff  = sbuf + 512;
    const float* b1eff = sbuf + 640;

    if (t < 64) scol[t] = colS[(e0 + t < E) ? (e0 + t) : (E - 1)];

    // per-lane col indices + early B prefetch (bf16)
    int cidx[4][4];
#pragma unroll
    for (int fr = 0; fr < 4; ++fr)
#pragma unroll
        for (int r = 0; r < 4; ++r) {
            int p  = e0 + 16 * fr + 4 * g + r;
            int pc = (p < E) ? p : (E - 1);
            cidx[fr][r] = colS[pc];
        }
    unsigned short bPre[4][2][4];
#pragma unroll
    for (int fr = 0; fr < 4; ++fr)
#pragma unroll
        for (int c = 0; c < 2; ++c)
#pragma unroll
            for (int r = 0; r < 4; ++r)
                bPre[fr][c][r] = Bsrc[(size_t)cidx[fr][r] * H + jb + 16 * c + c0];

    // stage e tile + gathered h[row] tile (pure bf16 copies)
    stage_copy(eb, sE, e0, E, t);
    stage_copy_gather(hb, rowS, sHt, e0, E, t);

    short8 wf[4][2];
    f32x4 acc[4][2];
    zero_acc(acc);
    load_wfrag(wfr + 2 * 2048, w, lane, wf);   // W3'
    __syncthreads();
    mfma_gemm(sE, wf, acc, lane);
    load_wfrag(wfr + 0 * 2048, w, lane, wf);   // W1'
    mfma_gemm(sHt, wf, acc, lane);
    __syncthreads();   // all reads of sE done -> safe to overwrite with e'

    // epilogue 1: e' = relu(acc + B[col] + beff) -> bf16 global + back to sE
    float s1[2] = {0.f, 0.f}, s2[2] = {0.f, 0.f};
#pragma unroll
    for (int fr = 0; fr < 4; ++fr)
#pragma unroll
        for (int c = 0; c < 2; ++c) {
            int j = jb + 16 * c + c0;
            float bej = beff[j];
#pragma unroll
            for (int r = 0; r < 4; ++r) {
                int Rl = 16 * fr + 4 * g + r;
                int p  = e0 + Rl;
                float v = acc[fr][c][r] + bf2f(bPre[fr][c][r]) + bej;
                v = fmaxf(v, 0.f);
                unsigned short vb = f2bf(v);
                if (p < E) {
                    eb[(size_t)p * H + j] = vb;
                    s1[c] += v;
                    s2[c] += v * v;
                }
                sE[(Rl << 7) + (j ^ ((Rl & 7) << 3))] = vb;
            }
        }
    __syncthreads();

    // GEMM2: m = e'@U2 + h[rowS]@U1'
    zero_acc(acc);
    load_wfrag(wfr + 4 * 2048, w, lane, wf);   // U2
    mfma_gemm(sE, wf, acc, lane);
    load_wfrag(wfr + 3 * 2048, w, lane, wf);   // U1'
    mfma_gemm(sHt, wf, acc, lane);
    __syncthreads();   // all GEMM2 LDS reads done -> mbuf overlay safe

    // epilogue 2: m -> mbuf (swizzled)
#pragma unroll
    for (int fr = 0; fr < 4; ++fr)
#pragma unroll
        for (int c = 0; c < 2; ++c) {
            int j = jb + 16 * c + c0;
            float b1j = b1eff[j];
#pragma unroll
            for (int r = 0; r < 4; ++r) {
                int Rl = 16 * fr + 4 * g + r;
                float v = fmaxf(acc[fr][c][r] + b1j, 0.f);
                mbuf[(Rl << 7) + (j ^ (((Rl >> 2) & 3) << 3))] = v;
            }
        }
    __syncthreads();

    // segmented reduction: thread j walks 64 sorted rows, 1 atomic per segment
    if (t < 128) {
        int j = t;
        float run = 0.f;
        int cur = scol[0];
        for (int row = 0; row < 64; ++row) {
            int cc = scol[row];
            float v = mbuf[(row << 7) + (j ^ (((row >> 2) & 3) << 3))];
            if (cc != cur) {
                atomicAdd(&aggsum[(size_t)cur * H + j], run);
                run = 0.f;
                cur = cc;
            }
            if (e0 + row < E) run += v;
        }
        atomicAdd(&aggsum[(size_t)cur * H + j], run);
    }

    // fused e'-stats
#pragma unroll
    for (int c = 0; c < 2; ++c) {
        float a = s1[c], b = s2[c];
        a += __shfl_xor(a, 16); a += __shfl_xor(a, 32);
        b += __shfl_xor(b, 16); b += __shfl_xor(b, 32);
        if (g == 0) {
            int j = jb + 16 * c + c0;
            atomicAdd(&eStats[j], a);
            atomicAdd(&eStats[H + j], b);
        }
    }
}

// ---------------------------------------------------------------------------
// Node update (in place, bf16 h): h = relu(h@V1' + agg@V2 + b2eff); fused stats
__global__ __launch_bounds__(256, 8) void node_kernel(unsigned short* hb,
                                                      const float* __restrict__ aggsum,
                                                      const int* __restrict__ cnt,
                                                      const short8* __restrict__ wfr,
                                                      const float* __restrict__ sbuf,
                                                      int M,
                                                      float* __restrict__ hStats)
{
    __shared__ __align__(16) unsigned short sA[64 * 128];
    const int t = threadIdx.x, lane = t & 63, w = t >> 6, jb = 32 * w;
    const int r0 = blockIdx.x * 64;
    const float* b2eff = sbuf + 768;
    stage_copy(hb, sA, r0, M, t);
    short8 wf[4][2];
    load_wfrag(wfr + 5 * 2048, w, lane, wf);   // V1'
    f32x4 acc[4][2];
    zero_acc(acc);
    __syncthreads();
    mfma_gemm(sA, wf, acc, lane);
    __syncthreads();   // h-tile reads done
    stage_agg_bf16(aggsum, cnt, sA, r0, M, t);
    load_wfrag(wfr + 6 * 2048, w, lane, wf);   // V2
    __syncthreads();
    mfma_gemm(sA, wf, acc, lane);
    const int g = lane >> 4, c0 = lane & 15;
    float s1[2] = {0.f, 0.f}, s2[2] = {0.f, 0.f};
#pragma unroll
    for (int fr = 0; fr < 4; ++fr)
#pragma unroll
        for (int c = 0; c < 2; ++c) {
            int j = jb + 16 * c + c0;
            float bj = b2eff[j];
#pragma unroll
            for (int r = 0; r < 4; ++r) {
                int row = r0 + 16 * fr + 4 * g + r;
                if (row < M) {
                    float v = fmaxf(acc[fr][c][r] + bj, 0.f);
                    hb[(size_t)row * H + j] = f2bf(v);
                    s1[c] += v;
                    s2[c] += v * v;
                }
            }
        }
#pragma unroll
    for (int c = 0; c < 2; ++c) {
        float a = s1[c], b = s2[c];
        a += __shfl_xor(a, 16); a += __shfl_xor(a, 32);
        b += __shfl_xor(b, 16); b += __shfl_xor(b, 32);
        if (g == 0) {
            int j = jb + 16 * c + c0;
            atomicAdd(&hStats[j], a);
            atomicAdd(&hStats[H + j], b);
        }
    }
}

// ---------------------------------------------------------------------------
// Final readout: out = [mean(h) | mean(e)] @ reg_w + reg_b
__global__ __launch_bounds__(256) void final_kernel(const float* __restrict__ hsum,
                                                    const float* __restrict__ esum,
                                                    const float* __restrict__ reg_w,
                                                    const float* __restrict__ reg_b,
                                                    float* __restrict__ out,
                                                    float invN, float invE)
{
    __shared__ float red[256];
    int t = threadIdx.x;
    float v = (t < 128) ? hsum[t] * invN * reg_w[t]
                        : esum[t - 128] * invE * reg_w[t];
    red[t] = v;
    __syncthreads();
    for (int s = 128; s > 0; s >>= 1) {
        if (t < s) red[t] += red[t + s];
        __syncthreads();
    }
    if (t == 0) out[0] = red[0] + reg_b[0];
}

// ---------------------------------------------------------------------------
extern "C" void kernel_launch(void* const* d_in, const int* in_sizes, int n_in,
                              void* d_out, int out_size, void* d_ws, size_t ws_size,
                              hipStream_t stream)
{
    const float* x          = (const float*)d_in[0];
    const int*   edge_index = (const int*)  d_in[1];
    const float* edge_attr  = (const float*)d_in[2];
    const float* enc_node_w = (const float*)d_in[3];
    const float* enc_node_b = (const float*)d_in[4];
    const float* enc_edge_w = (const float*)d_in[5];
    const float* enc_edge_b = (const float*)d_in[6];
    const float* edge_w     = (const float*)d_in[7];
    const float* edge_b     = (const float*)d_in[8];
    const float* n1_w       = (const float*)d_in[9];
    const float* n1_b       = (const float*)d_in[10];
    const float* n2_w       = (const float*)d_in[11];
    const float* n2_b       = (const float*)d_in[12];
    const float* bn_node_g  = (const float*)d_in[13];
    const float* bn_node_b  = (const float*)d_in[14];
    const float* bn_edge_g  = (const float*)d_in[15];
    const float* bn_edge_b  = (const float*)d_in[16];
    const float* reg_w      = (const float*)d_in[17];
    const float* reg_b      = (const float*)d_in[18];

    const int N = in_sizes[0] / F_IN;
    const int E = in_sizes[1] / 2;
    const size_t NH = (size_t)N * H;
    const size_t EH = (size_t)E * H;

    float* ws     = (float*)d_ws;
    float* aggsum = ws;                 // [N,128] f32
    float* statsA = aggsum + NH;        // 512
    float* statsB = statsA + 512;       // 512
    float* sbuf   = statsB + 512;       // 896 (s/t/beff/b1eff/b2eff)
    short8* wfr   = (short8*)(sbuf + 896);          // 7*2048 short8 = 224 KB
    unsigned short* hbuf = (unsigned short*)(wfr + 7 * 2048);  // [N,128] bf16
    unsigned short* ebuf = hbuf + NH;                          // [E,128] bf16 (col-sorted)
    unsigned short* Bbuf = ebuf + EH;                          // [N,128] bf16
    int*   cnt_i  = (int*)(Bbuf + NH);      // [N]
    int*   tmpc   = cnt_i + N;              // [N]
    int*   offs   = tmpc + N;               // [N+1]
    int*   sortedIds = offs + N + 1;        // [E]
    int*   rowS   = sortedIds + E;          // [E]
    int*   colS   = rowS + E;               // [E]

    const int* row_idx = edge_index;
    const int* col_idx = edge_index + E;
    const float invN = 1.f / (float)N;
    const float invE = 1.f / (float)E;

    // one-time: sort edges by col, build permuted index arrays
    (void)hipMemsetAsync(cnt_i, 0, (size_t)2 * N * sizeof(int), stream);
    hist_kernel<<<(E + 255) / 256, 256, 0, stream>>>(col_idx, cnt_i, E);
    scan_kernel<<<1, 1024, 0, stream>>>(cnt_i, offs, N);
    scatter_kernel<<<(E + 255) / 256, 256, 0, stream>>>(row_idx, col_idx, offs, tmpc,
                                                        sortedIds, rowS, colS, E);

    enc_kernel<<<(N + 1) / 2, 256, 0, stream>>>(x, enc_node_w, enc_node_b, hbuf, N);
    enc_gather_kernel<<<(E + 1) / 2, 256, 0, stream>>>(edge_attr, sortedIds,
                                                       enc_edge_w, enc_edge_b, ebuf, E);

    const int nodeBlocks = (N + 63) / 64;
    const int edgeBlocks = (E + 63) / 64;

    for (int i = 0; i < 3; ++i) {
        float*       Scur  = (i & 1) ? statsB : statsA;
        const float* Sprev = (i == 0) ? nullptr : ((i & 1) ? statsA : statsB);
        const float* We = edge_w + (size_t)i * 384 * H;
        const float* Wu = n1_w + (size_t)i * 256 * H;
        const float* Wv = n2_w + (size_t)i * 256 * H;
        prep_kernel<<<1, 128, 0, stream>>>(
            Sprev, Sprev ? Sprev + 256 : nullptr,
            bn_node_g, bn_node_b, bn_edge_g, bn_edge_b, invN, invE, sbuf);
        wfrag_kernel<<<10, 256, 0, stream>>>(We, Wu, Wv,
                                             edge_b + i * H, n1_b + i * H, n2_b + i * H,
                                             sbuf, wfr);
        (void)hipMemsetAsync(aggsum, 0, NH * sizeof(float), stream);
        (void)hipMemsetAsync(Scur, 0, 512 * sizeof(float), stream);
        bk_kernel<<<nodeBlocks, 256, 0, stream>>>(hbuf, wfr + 1 * 2048, Bbuf, N);
        edge_kernel<<<edgeBlocks, 256, 0, stream>>>(
            ebuf, rowS, colS, hbuf, Bbuf, wfr, sbuf, aggsum, E, Scur + 256);
        node_kernel<<<nodeBlocks, 256, 0, stream>>>(
            hbuf, aggsum, cnt_i, wfr, sbuf, N, Scur);
    }
    // i=2 wrote statsA
    final_kernel<<<1, 256, 0, stream>>>(statsA, statsA + 256, reg_w, reg_b,
                                        (float*)d_out, invN, invE);
}

// Round 15
// 828.990 us; speedup vs baseline: 1.0825x; 1.0810x over previous
//
#include <hip/hip_runtime.h>

#define H 128
#define F_IN 16
#define BNEPS 1e-5f

typedef __attribute__((ext_vector_type(8))) short short8;
typedef __attribute__((ext_vector_type(4))) float f32x4;

// f32 -> bf16 round-to-nearest-even
__device__ __forceinline__ unsigned short f2bf(float f)
{
    unsigned u = __builtin_bit_cast(unsigned, f);
    u += 0x7FFFu + ((u >> 16) & 1u);
    return (unsigned short)(u >> 16);
}
__device__ __forceinline__ float bf2f(unsigned short h)
{
    return __builtin_bit_cast(float, (unsigned)h << 16);
}

// BN affine params for feature j into LDS: s[j], t[j] (identity if S==nullptr)
__device__ __forceinline__ void bn_param(const float* __restrict__ S,
                                         const float* __restrict__ g,
                                         const float* __restrict__ b,
                                         float invM, int j,
                                         float* __restrict__ sS, float* __restrict__ sT)
{
    float s = 1.f, tt = 0.f;
    if (S) {
        float mean = S[j] * invM;
        float var  = S[H + j] * invM - mean * mean;
        s  = rsqrtf(var + BNEPS) * g[j];
        tt = b[j] - mean * s;
    }
    sS[j] = s;
    sT[j] = tt;
}

// ---------------------------------------------------------------------------
// Stage a 64x128 bf16 tile with per-feature affine (s,t from LDS) into
// swizzled LDS. element (row,k) -> ushort idx row*128 + (k ^ ((row&7)<<3))
__device__ __forceinline__ void stage_aff(const unsigned short* __restrict__ src,
                                          unsigned short* sA, int r0, int M, int t,
                                          const float* __restrict__ sS,
                                          const float* __restrict__ sT)
{
#pragma unroll
    for (int i = 0; i < 4; ++i) {
        int cid  = t + 256 * i;
        int row  = cid >> 4;
        int ck   = cid & 15;
        int grow = r0 + row;
        short8 v = (short8)0;
        if (grow < M) {
            v = *(const short8*)(src + (size_t)grow * H + ck * 8);
            int j0 = ck * 8;
#pragma unroll
            for (int j = 0; j < 8; ++j)
                v[j] = (short)f2bf(bf2f((unsigned short)v[j]) * sS[j0 + j] + sT[j0 + j]);
        }
        *(short8*)(sA + (row << 7) + ((ck ^ (row & 7)) << 3)) = v;
    }
}

// Gather variant: tile row i holds src[idx[p0+i]], same affine.
__device__ __forceinline__ void stage_aff_gather(const unsigned short* __restrict__ src,
                                                 const int* __restrict__ idx,
                                                 unsigned short* sA, int p0, int M, int t,
                                                 const float* __restrict__ sS,
                                                 const float* __restrict__ sT)
{
#pragma unroll
    for (int i = 0; i < 4; ++i) {
        int cid = t + 256 * i;
        int row = cid >> 4;
        int ck  = cid & 15;
        int p   = p0 + row;
        short8 v = (short8)0;
        if (p < M) {
            v = *(const short8*)(src + (size_t)idx[p] * H + ck * 8);
            int j0 = ck * 8;
#pragma unroll
            for (int j = 0; j < 8; ++j)
                v[j] = (short)f2bf(bf2f((unsigned short)v[j]) * sS[j0 + j] + sT[j0 + j]);
        }
        *(short8*)(sA + (row << 7) + ((ck ^ (row & 7)) << 3)) = v;
    }
}

// value = aggsum[row][k] / max(cnt[row],1) -> bf16 (aggsum f32, cnt int)
__device__ __forceinline__ void stage_agg_bf16(const float* __restrict__ aggsum,
                                               const int* __restrict__ cnt,
                                               unsigned short* sA, int r0, int M, int t)
{
#pragma unroll
    for (int i = 0; i < 4; ++i) {
        int cid  = t + 256 * i;
        int row  = cid >> 4;
        int ck   = cid & 15;
        int grow = r0 + row;
        short8 ph = (short8)0;
        if (grow < M) {
            const float4* q = (const float4*)(aggsum + (size_t)grow * H + ck * 8);
            float4 a = q[0], b = q[1];
            int c = cnt[grow];
            float inv = 1.f / (float)(c > 1 ? c : 1);
            float xs[8] = {a.x * inv, a.y * inv, a.z * inv, a.w * inv,
                           b.x * inv, b.y * inv, b.z * inv, b.w * inv};
#pragma unroll
            for (int j = 0; j < 8; ++j) ph[j] = (short)f2bf(xs[j]);
        }
        *(short8*)(sA + (row << 7) + ((ck ^ (row & 7)) << 3)) = ph;
    }
}

// ---------------------------------------------------------------------------
// One-time weight bf16 fragment precompute (21 matrices, unscaled).
// m: layer=m/7, k=m%7: k<3 -> edge_w{W1,W2,W3}; k<5 -> n1_w{U1,U2}; else {V1,V2}.
// Per matrix: 2048 short8; entry idx=((jbB*4+s)*2+c)*64+lane holds
// W[32s+8g+j][jbB*32+16c+c0].
__global__ __launch_bounds__(256) void wbf16_kernel(const float* __restrict__ edge_w,
                                                    const float* __restrict__ n1_w,
                                                    const float* __restrict__ n2_w,
                                                    short8* __restrict__ out)
{
    int m = blockIdx.x;
    int layer = m / 7, k = m % 7;
    const float* W = (k < 3) ? edge_w + (size_t)layer * 384 * H + (size_t)k * H * H
                   : (k < 5) ? n1_w + (size_t)layer * 256 * H + (size_t)(k - 3) * H * H
                             : n2_w + (size_t)layer * 256 * H + (size_t)(k - 5) * H * H;
    short8* oh = out + (size_t)m * 2048;
    for (int e = threadIdx.x; e < 2048; e += 256) {
        int jbB = e >> 9, s = (e >> 7) & 3, c = (e >> 6) & 1, lane = e & 63;
        int g = lane >> 4, c0 = lane & 15;
        short8 hi;
#pragma unroll
        for (int j = 0; j < 8; ++j)
            hi[j] = (short)f2bf(W[(size_t)(32 * s + 8 * g + j) * H + jbB * 32 + 16 * c + c0]);
        oh[e] = hi;
    }
}

// Load precomputed bf16 fragments: 8 coalesced 16B loads.
__device__ __forceinline__ void load_wfrag(const short8* __restrict__ Wp, int jbB,
                                           int lane, short8 wf[4][2])
{
#pragma unroll
    for (int s = 0; s < 4; ++s)
#pragma unroll
        for (int c = 0; c < 2; ++c)
            wf[s][c] = Wp[((jbB * 4 + s) * 2 + c) * 64 + lane];
}

// acc += sA(64x128 bf16, swizzled) @ Wf(128x32 bf16)
__device__ __forceinline__ void mfma_gemm(const unsigned short* sA, const short8 wf[4][2],
                                          f32x4 acc[4][2], int lane)
{
    const int g = lane >> 4, r = lane & 15;
#pragma unroll
    for (int s = 0; s < 4; ++s) {
        short8 a4[4];
#pragma unroll
        for (int fr = 0; fr < 4; ++fr) {
            int row = 16 * fr + r;
            int ck  = (4 * s + g) ^ (row & 7);
            a4[fr] = *(const short8*)(sA + (row << 7) + (ck << 3));
        }
#pragma unroll
        for (int fr = 0; fr < 4; ++fr)
#pragma unroll
            for (int c = 0; c < 2; ++c)
                acc[fr][c] = __builtin_amdgcn_mfma_f32_16x16x32_bf16(a4[fr], wf[s][c],
                                                                     acc[fr][c], 0, 0, 0);
    }
}

__device__ __forceinline__ void zero_acc(f32x4 acc[4][2])
{
#pragma unroll
    for (int fr = 0; fr < 4; ++fr)
#pragma unroll
        for (int c = 0; c < 2; ++c) {
            acc[fr][c][0] = 0.f; acc[fr][c][1] = 0.f;
            acc[fr][c][2] = 0.f; acc[fr][c][3] = 0.f;
        }
}

// ---------------------------------------------------------------------------
// One-time sort machinery (edge_index is layer-invariant)
__global__ __launch_bounds__(256) void hist_kernel(const int* __restrict__ col,
                                                   int* __restrict__ cnt, int E)
{
    int e = blockIdx.x * 256 + threadIdx.x;
    if (e < E) atomicAdd(&cnt[col[e]], 1);
}

__global__ __launch_bounds__(1024) void scan_kernel(const int* __restrict__ cnt,
                                                    int* __restrict__ offs, int Nn)
{
    __shared__ int ls[1024];
    int t = threadIdx.x;
    int per = (Nn + 1023) / 1024;
    int base = t * per;
    int s = 0;
    for (int k = 0; k < per; ++k) {
        int i = base + k;
        if (i < Nn) s += cnt[i];
    }
    ls[t] = s;
    __syncthreads();
    for (int d = 1; d < 1024; d <<= 1) {
        int u = (t >= d) ? ls[t - d] : 0;
        __syncthreads();
        ls[t] += u;
        __syncthreads();
    }
    int run = ls[t] - s;
    for (int k = 0; k < per; ++k) {
        int i = base + k;
        if (i < Nn) {
            offs[i] = run;
            run += cnt[i];
        }
    }
}

__global__ __launch_bounds__(256) void scatter_kernel(const int* __restrict__ row,
                                                      const int* __restrict__ col,
                                                      const int* __restrict__ offs,
                                                      int* __restrict__ tmpc,
                                                      int* __restrict__ sortedIds,
                                                      int* __restrict__ rowS,
                                                      int* __restrict__ colS, int E)
{
    int e = blockIdx.x * 256 + threadIdx.x;
    if (e < E) {
        int c = col[e];
        int p = offs[c] + atomicAdd(&tmpc[c], 1);
        sortedIds[p] = e;
        rowS[p] = row[e];
        colS[p] = c;
    }
}

// ---------------------------------------------------------------------------
// Encoder: out(bf16) = relu(X[M,16] @ W[16,128] + b)
__global__ __launch_bounds__(256) void enc_kernel(const float* __restrict__ X,
                                                  const float* __restrict__ W,
                                                  const float* __restrict__ bias,
                                                  unsigned short* __restrict__ out, int M)
{
    __shared__ float sW[F_IN * H];
    __shared__ float sb[H];
    int t = threadIdx.x;
    reinterpret_cast<float4*>(sW)[t]       = reinterpret_cast<const float4*>(W)[t];
    reinterpret_cast<float4*>(sW)[t + 256] = reinterpret_cast<const float4*>(W)[t + 256];
    if (t < H) sb[t] = bias[t];
    __syncthreads();
    int row = blockIdx.x * 2 + (t >> 7);
    if (row >= M) return;
    int j = t & 127;
    float acc = sb[j];
#pragma unroll
    for (int k = 0; k < F_IN; ++k)
        acc += X[(size_t)row * F_IN + k] * sW[k * H + j];
    out[(size_t)row * H + j] = f2bf(fmaxf(acc, 0.f));
}

// Gather-encoder: out[p](bf16) = relu(X[sortedIds[p],16] @ W + b)
__global__ __launch_bounds__(256) void enc_gather_kernel(const float* __restrict__ X,
                                                         const int* __restrict__ sortedIds,
                                                         const float* __restrict__ W,
                                                         const float* __restrict__ bias,
                                                         unsigned short* __restrict__ out,
                                                         int M)
{
    __shared__ float sW[F_IN * H];
    __shared__ float sb[H];
    int t = threadIdx.x;
    reinterpret_cast<float4*>(sW)[t]       = reinterpret_cast<const float4*>(W)[t];
    reinterpret_cast<float4*>(sW)[t + 256] = reinterpret_cast<const float4*>(W)[t + 256];
    if (t < H) sb[t] = bias[t];
    __syncthreads();
    int p = blockIdx.x * 2 + (t >> 7);
    if (p >= M) return;
    int src = sortedIds[p];
    int j = t & 127;
    float acc = sb[j];
#pragma unroll
    for (int k = 0; k < F_IN; ++k)
        acc += X[(size_t)src * F_IN + k] * sW[k * H + j];
    out[(size_t)p * H + j] = f2bf(fmaxf(acc, 0.f));
}

// ---------------------------------------------------------------------------
// B precompute: B(bf16) = bn(h) @ W2  (BN applied at staging)
__global__ __launch_bounds__(256, 8) void bk_kernel(const unsigned short* __restrict__ hb,
                                                    const short8* __restrict__ W2p,
                                                    unsigned short* __restrict__ Bout, int M,
                                                    const float* __restrict__ Sh,
                                                    const float* __restrict__ gh,
                                                    const float* __restrict__ bh,
                                                    float invN)
{
    __shared__ __align__(16) unsigned short sA[64 * 128];
    __shared__ float bnp[256];
    const int t = threadIdx.x, lane = t & 63, w = t >> 6, jb = 32 * w;
    const int r0 = blockIdx.x * 64;
    if (t < 128) bn_param(Sh, gh, bh, invN, t, bnp, bnp + 128);
    __syncthreads();
    stage_aff(hb, sA, r0, M, t, bnp, bnp + 128);
    const int g = lane >> 4, c0 = lane & 15;
    short8 wf[4][2];
    load_wfrag(W2p, w, lane, wf);
    f32x4 acc[4][2];
    zero_acc(acc);
    __syncthreads();
    mfma_gemm(sA, wf, acc, lane);
#pragma unroll
    for (int fr = 0; fr < 4; ++fr)
#pragma unroll
        for (int c = 0; c < 2; ++c) {
            int j = jb + 16 * c + c0;
#pragma unroll
            for (int r = 0; r < 4; ++r) {
                int row = r0 + 16 * fr + 4 * g + r;
                if (row < M) Bout[(size_t)row * H + j] = f2bf(acc[fr][c][r]);
            }
        }
}

// ---------------------------------------------------------------------------
// Fused edge kernel (bf16 e col-sorted; BN applied at staging):
//   e'[p] = relu(bn_e(e[p])@W3 + bn_h(h[rowS])@W1 + B[colS] + be)
//   m     = relu(e'@U2 + bn_h(h[rowS])@U1 + b1)
//   aggsum[col] += segment-reduced m ; fused e'-stats
__global__ __launch_bounds__(256, 4) void edge_kernel(unsigned short* eb,
                                                      const int* __restrict__ rowS,
                                                      const int* __restrict__ colS,
                                                      const unsigned short* __restrict__ hb,
                                                      const unsigned short* __restrict__ Bsrc,
                                                      const short8* __restrict__ wfrL,
                                                      const float* __restrict__ be,
                                                      const float* __restrict__ b1,
                                                      float* __restrict__ aggsum, int E,
                                                      const float* __restrict__ Sh,
                                                      const float* __restrict__ gh,
                                                      const float* __restrict__ bh,
                                                      float invN,
                                                      const float* __restrict__ Se,
                                                      const float* __restrict__ ge,
                                                      const float* __restrict__ beB,
                                                      float invE,
                                                      float* __restrict__ eStats)
{
    __shared__ __align__(16) unsigned char smem[64 * 128 * 4 + 256 + 2048];
    unsigned short* sE  = (unsigned short*)smem;          // 16 KB  e (bf16)
    unsigned short* sHt = sE + 64 * 128;                  // 16 KB  h[row] (bf16)
    float*          mbuf = (float*)smem;                  // 32 KB overlay (post-GEMM2)
    int*            scol = (int*)(smem + 64 * 128 * 4);   // 256 B
    float*          bnp  = (float*)(smem + 64 * 128 * 4 + 256);  // 2 KB

    const int t = threadIdx.x, lane = t & 63, w = t >> 6, jb = 32 * w;
    const int e0 = blockIdx.x * 64;
    const int g = lane >> 4, c0 = lane & 15;

    if (t < 64) scol[t] = colS[(e0 + t < E) ? (e0 + t) : (E - 1)];
    if (t < 128) bn_param(Sh, gh, bh, invN, t, bnp, bnp + 128);
    else         bn_param(Se, ge, beB, invE, t - 128, bnp + 256, bnp + 384);

    // per-lane col indices + early B prefetch (bf16, no LDS dependency)
    int cidx[4][4];
#pragma unroll
    for (int fr = 0; fr < 4; ++fr)
#pragma unroll
        for (int r = 0; r < 4; ++r) {
            int p  = e0 + 16 * fr + 4 * g + r;
            int pc = (p < E) ? p : (E - 1);
            cidx[fr][r] = colS[pc];
        }
    unsigned short bPre[4][2][4];
#pragma unroll
    for (int fr = 0; fr < 4; ++fr)
#pragma unroll
        for (int c = 0; c < 2; ++c)
#pragma unroll
            for (int r = 0; r < 4; ++r)
                bPre[fr][c][r] = Bsrc[(size_t)cidx[fr][r] * H + jb + 16 * c + c0];

    __syncthreads();   // bnp ready
    stage_aff(eb, sE, e0, E, t, bnp + 256, bnp + 384);
    stage_aff_gather(hb, rowS, sHt, e0, E, t, bnp, bnp + 128);

    short8 wf[4][2];
    f32x4 acc[4][2];
    zero_acc(acc);
    load_wfrag(wfrL + 2 * 2048, w, lane, wf);   // W3
    __syncthreads();
    mfma_gemm(sE, wf, acc, lane);
    load_wfrag(wfrL + 0 * 2048, w, lane, wf);   // W1
    mfma_gemm(sHt, wf, acc, lane);
    __syncthreads();   // all reads of sE done -> safe to overwrite with e'

    // epilogue 1: e' = relu(acc + B[col] + be) -> bf16 global + back to sE
    float s1[2] = {0.f, 0.f}, s2[2] = {0.f, 0.f};
#pragma unroll
    for (int fr = 0; fr < 4; ++fr)
#pragma unroll
        for (int c = 0; c < 2; ++c) {
            int j = jb + 16 * c + c0;
            float bej = be[j];
#pragma unroll
            for (int r = 0; r < 4; ++r) {
                int Rl = 16 * fr + 4 * g + r;
                int p  = e0 + Rl;
                float v = acc[fr][c][r] + bf2f(bPre[fr][c][r]) + bej;
                v = fmaxf(v, 0.f);
                unsigned short vb = f2bf(v);
                if (p < E) {
                    eb[(size_t)p * H + j] = vb;
                    s1[c] += v;
                    s2[c] += v * v;
                }
                sE[(Rl << 7) + (j ^ ((Rl & 7) << 3))] = vb;
            }
        }
    __syncthreads();

    // GEMM2: m = e'@U2 + bn_h(h[rowS])@U1
    zero_acc(acc);
    load_wfrag(wfrL + 4 * 2048, w, lane, wf);   // U2
    mfma_gemm(sE, wf, acc, lane);
    load_wfrag(wfrL + 3 * 2048, w, lane, wf);   // U1
    mfma_gemm(sHt, wf, acc, lane);
    __syncthreads();   // all GEMM2 LDS reads done -> mbuf overlay safe

    // epilogue 2: m -> mbuf (swizzled)
#pragma unroll
    for (int fr = 0; fr < 4; ++fr)
#pragma unroll
        for (int c = 0; c < 2; ++c) {
            int j = jb + 16 * c + c0;
            float b1j = b1[j];
#pragma unroll
            for (int r = 0; r < 4; ++r) {
                int Rl = 16 * fr + 4 * g + r;
                float v = fmaxf(acc[fr][c][r] + b1j, 0.f);
                mbuf[(Rl << 7) + (j ^ (((Rl >> 2) & 3) << 3))] = v;
            }
        }
    __syncthreads();

    // segmented reduction: thread j walks 64 sorted rows, 1 atomic per segment
    if (t < 128) {
        int j = t;
        float run = 0.f;
        int cur = scol[0];
        for (int row = 0; row < 64; ++row) {
            int cc = scol[row];
            float v = mbuf[(row << 7) + (j ^ (((row >> 2) & 3) << 3))];
            if (cc != cur) {
                atomicAdd(&aggsum[(size_t)cur * H + j], run);
                run = 0.f;
                cur = cc;
            }
            if (e0 + row < E) run += v;
        }
        atomicAdd(&aggsum[(size_t)cur * H + j], run);
    }

    // fused e'-stats
#pragma unroll
    for (int c = 0; c < 2; ++c) {
        float a = s1[c], b = s2[c];
        a += __shfl_xor(a, 16); a += __shfl_xor(a, 32);
        b += __shfl_xor(b, 16); b += __shfl_xor(b, 32);
        if (g == 0) {
            int j = jb + 16 * c + c0;
            atomicAdd(&eStats[j], a);
            atomicAdd(&eStats[H + j], b);
        }
    }
}

// ---------------------------------------------------------------------------
// Node update (in place, bf16 h): h = relu(bn_h(h)@V1 + agg@V2 + b2);
// fused h-stats; zeroes its aggsum rows for the next layer.
__global__ __launch_bounds__(256, 8) void node_kernel(unsigned short* hb,
                                                      float* __restrict__ aggsum,
                                                      const int* __restrict__ cnt,
                                                      const short8* __restrict__ wfrL,
                                                      const float* __restrict__ b2, int M,
                                                      const float* __restrict__ Sh,
                                                      const float* __restrict__ gh,
                                                      const float* __restrict__ bh,
                                                      float invN,
                                                      float* __restrict__ hStats)
{
    __shared__ __align__(16) unsigned short sA[64 * 128];
    __shared__ float bnp[256];
    const int t = threadIdx.x, lane = t & 63, w = t >> 6, jb = 32 * w;
    const int r0 = blockIdx.x * 64;
    if (t < 128) bn_param(Sh, gh, bh, invN, t, bnp, bnp + 128);
    __syncthreads();
    stage_aff(hb, sA, r0, M, t, bnp, bnp + 128);
    short8 wf[4][2];
    load_wfrag(wfrL + 5 * 2048, w, lane, wf);   // V1
    f32x4 acc[4][2];
    zero_acc(acc);
    __syncthreads();
    mfma_gemm(sA, wf, acc, lane);
    __syncthreads();   // h-tile reads done
    stage_agg_bf16(aggsum, cnt, sA, r0, M, t);
    // zero the aggsum rows this block consumed (next layer starts from 0)
#pragma unroll
    for (int i = 0; i < 4; ++i) {
        int cid = t + 256 * i;
        int row = cid >> 4, ck = cid & 15, grow = r0 + row;
        if (grow < M) {
            float4* q = (float4*)(aggsum + (size_t)grow * H + ck * 8);
            q[0] = make_float4(0.f, 0.f, 0.f, 0.f);
            q[1] = make_float4(0.f, 0.f, 0.f, 0.f);
        }
    }
    load_wfrag(wfrL + 6 * 2048, w, lane, wf);   // V2
    __syncthreads();
    mfma_gemm(sA, wf, acc, lane);
    const int g = lane >> 4, c0 = lane & 15;
    float s1[2] = {0.f, 0.f}, s2[2] = {0.f, 0.f};
#pragma unroll
    for (int fr = 0; fr < 4; ++fr)
#pragma unroll
        for (int c = 0; c < 2; ++c) {
            int j = jb + 16 * c + c0;
            float bj = b2[j];
#pragma unroll
            for (int r = 0; r < 4; ++r) {
                int row = r0 + 16 * fr + 4 * g + r;
                if (row < M) {
                    float v = fmaxf(acc[fr][c][r] + bj, 0.f);
                    hb[(size_t)row * H + j] = f2bf(v);
                    s1[c] += v;
                    s2[c] += v * v;
                }
            }
        }
#pragma unroll
    for (int c = 0; c < 2; ++c) {
        float a = s1[c], b = s2[c];
        a += __shfl_xor(a, 16); a += __shfl_xor(a, 32);
        b += __shfl_xor(b, 16); b += __shfl_xor(b, 32);
        if (g == 0) {
            int j = jb + 16 * c + c0;
            atomicAdd(&hStats[j], a);
            atomicAdd(&hStats[H + j], b);
        }
    }
}

// ---------------------------------------------------------------------------
// Final readout: out = [mean(h) | mean(e)] @ reg_w + reg_b
__global__ __launch_bounds__(256) void final_kernel(const float* __restrict__ hsum,
                                                    const float* __restrict__ esum,
                                                    const float* __restrict__ reg_w,
                                                    const float* __restrict__ reg_b,
                                                    float* __restrict__ out,
                                                    float invN, float invE)
{
    __shared__ float red[256];
    int t = threadIdx.x;
    float v = (t < 128) ? hsum[t] * invN * reg_w[t]
                        : esum[t - 128] * invE * reg_w[t];
    red[t] = v;
    __syncthreads();
    for (int s = 128; s > 0; s >>= 1) {
        if (t < s) red[t] += red[t + s];
        __syncthreads();
    }
    if (t == 0) out[0] = red[0] + reg_b[0];
}

// ---------------------------------------------------------------------------
extern "C" void kernel_launch(void* const* d_in, const int* in_sizes, int n_in,
                              void* d_out, int out_size, void* d_ws, size_t ws_size,
                              hipStream_t stream)
{
    const float* x          = (const float*)d_in[0];
    const int*   edge_index = (const int*)  d_in[1];
    const float* edge_attr  = (const float*)d_in[2];
    const float* enc_node_w = (const float*)d_in[3];
    const float* enc_node_b = (const float*)d_in[4];
    const float* enc_edge_w = (const float*)d_in[5];
    const float* enc_edge_b = (const float*)d_in[6];
    const float* edge_w     = (const float*)d_in[7];
    const float* edge_b     = (const float*)d_in[8];
    const float* n1_w       = (const float*)d_in[9];
    const float* n1_b       = (const float*)d_in[10];
    const float* n2_w       = (const float*)d_in[11];
    const float* n2_b       = (const float*)d_in[12];
    const float* bn_node_g  = (const float*)d_in[13];
    const float* bn_node_b  = (const float*)d_in[14];
    const float* bn_edge_g  = (const float*)d_in[15];
    const float* bn_edge_b  = (const float*)d_in[16];
    const float* reg_w      = (const float*)d_in[17];
    const float* reg_b      = (const float*)d_in[18];

    const int N = in_sizes[0] / F_IN;
    const int E = in_sizes[1] / 2;
    const size_t NH = (size_t)N * H;
    const size_t EH = (size_t)E * H;

    float* ws     = (float*)d_ws;
    float* aggsum = ws;                 // [N,128] f32 (zeroed once; node re-zeroes)
    float* statsA = aggsum + NH;        // 512
    float* statsB = statsA + 512;       // 512
    short8* wfr   = (short8*)(statsB + 512);        // 21*2048 short8 = 672 KB
    unsigned short* hbuf = (unsigned short*)(wfr + 21 * 2048);  // [N,128] bf16
    unsigned short* ebuf = hbuf + NH;                           // [E,128] bf16 (col-sorted)
    unsigned short* Bbuf = ebuf + EH;                           // [N,128] bf16
    int*   cnt_i  = (int*)(Bbuf + NH);      // [N]
    int*   tmpc   = cnt_i + N;              // [N]
    int*   offs   = tmpc + N;               // [N+1]
    int*   sortedIds = offs + N + 1;        // [E]
    int*   rowS   = sortedIds + E;          // [E]
    int*   colS   = rowS + E;               // [E]

    const int* row_idx = edge_index;
    const int* col_idx = edge_index + E;
    const float invN = 1.f / (float)N;
    const float invE = 1.f / (float)E;

    // one-time: sort edges by col; bf16 weight fragments; encoders
    (void)hipMemsetAsync(cnt_i, 0, (size_t)2 * N * sizeof(int), stream);
    (void)hipMemsetAsync(aggsum, 0, NH * sizeof(float), stream);
    hist_kernel<<<(E + 255) / 256, 256, 0, stream>>>(col_idx, cnt_i, E);
    scan_kernel<<<1, 1024, 0, stream>>>(cnt_i, offs, N);
    scatter_kernel<<<(E + 255) / 256, 256, 0, stream>>>(row_idx, col_idx, offs, tmpc,
                                                        sortedIds, rowS, colS, E);
    wbf16_kernel<<<21, 256, 0, stream>>>(edge_w, n1_w, n2_w, wfr);

    enc_kernel<<<(N + 1) / 2, 256, 0, stream>>>(x, enc_node_w, enc_node_b, hbuf, N);
    enc_gather_kernel<<<(E + 1) / 2, 256, 0, stream>>>(edge_attr, sortedIds,
                                                       enc_edge_w, enc_edge_b, ebuf, E);

    const int nodeBlocks = (N + 63) / 64;
    const int edgeBlocks = (E + 63) / 64;

    for (int i = 0; i < 3; ++i) {
        float*       Scur  = (i & 1) ? statsB : statsA;
        const float* Sprev = (i == 0) ? nullptr : ((i & 1) ? statsA : statsB);
        const float* Sh = Sprev;
        const float* Se = Sprev ? Sprev + 256 : nullptr;
        const short8* wfrL = wfr + (size_t)i * 7 * 2048;
        (void)hipMemsetAsync(Scur, 0, 512 * sizeof(float), stream);
        bk_kernel<<<nodeBlocks, 256, 0, stream>>>(
            hbuf, wfrL + 1 * 2048, Bbuf, N, Sh, bn_node_g, bn_node_b, invN);
        edge_kernel<<<edgeBlocks, 256, 0, stream>>>(
            ebuf, rowS, colS, hbuf, Bbuf, wfrL,
            edge_b + i * H, n1_b + i * H,
            aggsum, E,
            Sh, bn_node_g, bn_node_b, invN,
            Se, bn_edge_g, bn_edge_b, invE,
            Scur + 256);
        node_kernel<<<nodeBlocks, 256, 0, stream>>>(
            hbuf, aggsum, cnt_i, wfrL, n2_b + i * H, N,
            Sh, bn_node_g, bn_node_b, invN,
            Scur);
    }
    // i=2 wrote statsA
    final_kernel<<<1, 256, 0, stream>>>(statsA, statsA + 256, reg_w, reg_b,
                                        (float*)d_out, invN, invE);
}

// Round 16
// 814.962 us; speedup vs baseline: 1.1012x; 1.0172x over previous
//
#include <hip/hip_runtime.h>

#define H 128
#define F_IN 16
#define BNEPS 1e-5f

typedef __attribute__((ext_vector_type(8))) short short8;
typedef __attribute__((ext_vector_type(4))) float f32x4;

// f32 -> bf16 round-to-nearest-even
__device__ __forceinline__ unsigned short f2bf(float f)
{
    unsigned u = __builtin_bit_cast(unsigned, f);
    u += 0x7FFFu + ((u >> 16) & 1u);
    return (unsigned short)(u >> 16);
}
__device__ __forceinline__ float bf2f(unsigned short h)
{
    return __builtin_bit_cast(float, (unsigned)h << 16);
}

// BN affine params for feature j into LDS: s[j], t[j] (identity if S==nullptr)
__device__ __forceinline__ void bn_param(const float* __restrict__ S,
                                         const float* __restrict__ g,
                                         const float* __restrict__ b,
                                         float invM, int j,
                                         float* __restrict__ sS, float* __restrict__ sT)
{
    float s = 1.f, tt = 0.f;
    if (S) {
        float mean = S[j] * invM;
        float var  = S[H + j] * invM - mean * mean;
        s  = rsqrtf(var + BNEPS) * g[j];
        tt = b[j] - mean * s;
    }
    sS[j] = s;
    sT[j] = tt;
}

// ---------------------------------------------------------------------------
// Stage a 64x128 bf16 tile with per-feature affine (s,t from LDS) into
// swizzled LDS. element (row,k) -> ushort idx row*128 + (k ^ ((row&7)<<3))
__device__ __forceinline__ void stage_aff(const unsigned short* __restrict__ src,
                                          unsigned short* sA, int r0, int M, int t,
                                          const float* __restrict__ sS,
                                          const float* __restrict__ sT)
{
#pragma unroll
    for (int i = 0; i < 4; ++i) {
        int cid  = t + 256 * i;
        int row  = cid >> 4;
        int ck   = cid & 15;
        int grow = r0 + row;
        short8 v = (short8)0;
        if (grow < M) {
            v = *(const short8*)(src + (size_t)grow * H + ck * 8);
            int j0 = ck * 8;
#pragma unroll
            for (int j = 0; j < 8; ++j)
                v[j] = (short)f2bf(bf2f((unsigned short)v[j]) * sS[j0 + j] + sT[j0 + j]);
        }
        *(short8*)(sA + (row << 7) + ((ck ^ (row & 7)) << 3)) = v;
    }
}

// Gather variant: tile row i holds src[idx[p0+i]], same affine.
__device__ __forceinline__ void stage_aff_gather(const unsigned short* __restrict__ src,
                                                 const int* __restrict__ idx,
                                                 unsigned short* sA, int p0, int M, int t,
                                                 const float* __restrict__ sS,
                                                 const float* __restrict__ sT)
{
#pragma unroll
    for (int i = 0; i < 4; ++i) {
        int cid = t + 256 * i;
        int row = cid >> 4;
        int ck  = cid & 15;
        int p   = p0 + row;
        short8 v = (short8)0;
        if (p < M) {
            v = *(const short8*)(src + (size_t)idx[p] * H + ck * 8);
            int j0 = ck * 8;
#pragma unroll
            for (int j = 0; j < 8; ++j)
                v[j] = (short)f2bf(bf2f((unsigned short)v[j]) * sS[j0 + j] + sT[j0 + j]);
        }
        *(short8*)(sA + (row << 7) + ((ck ^ (row & 7)) << 3)) = v;
    }
}

// aggsum already holds per-node MEANS -> just convert to bf16
__device__ __forceinline__ void stage_agg_bf16(const float* __restrict__ aggsum,
                                               unsigned short* sA, int r0, int M, int t)
{
#pragma unroll
    for (int i = 0; i < 4; ++i) {
        int cid  = t + 256 * i;
        int row  = cid >> 4;
        int ck   = cid & 15;
        int grow = r0 + row;
        short8 ph = (short8)0;
        if (grow < M) {
            const float4* q = (const float4*)(aggsum + (size_t)grow * H + ck * 8);
            float4 a = q[0], b = q[1];
            float xs[8] = {a.x, a.y, a.z, a.w, b.x, b.y, b.z, b.w};
#pragma unroll
            for (int j = 0; j < 8; ++j) ph[j] = (short)f2bf(xs[j]);
        }
        *(short8*)(sA + (row << 7) + ((ck ^ (row & 7)) << 3)) = ph;
    }
}

// ---------------------------------------------------------------------------
// One-time weight bf16 fragment precompute (21 matrices, unscaled).
__global__ __launch_bounds__(256) void wbf16_kernel(const float* __restrict__ edge_w,
                                                    const float* __restrict__ n1_w,
                                                    const float* __restrict__ n2_w,
                                                    short8* __restrict__ out)
{
    int m = blockIdx.x;
    int layer = m / 7, k = m % 7;
    const float* W = (k < 3) ? edge_w + (size_t)layer * 384 * H + (size_t)k * H * H
                   : (k < 5) ? n1_w + (size_t)layer * 256 * H + (size_t)(k - 3) * H * H
                             : n2_w + (size_t)layer * 256 * H + (size_t)(k - 5) * H * H;
    short8* oh = out + (size_t)m * 2048;
    for (int e = threadIdx.x; e < 2048; e += 256) {
        int jbB = e >> 9, s = (e >> 7) & 3, c = (e >> 6) & 1, lane = e & 63;
        int g = lane >> 4, c0 = lane & 15;
        short8 hi;
#pragma unroll
        for (int j = 0; j < 8; ++j)
            hi[j] = (short)f2bf(W[(size_t)(32 * s + 8 * g + j) * H + jbB * 32 + 16 * c + c0]);
        oh[e] = hi;
    }
}

// Load precomputed bf16 fragments: 8 coalesced 16B loads.
__device__ __forceinline__ void load_wfrag(const short8* __restrict__ Wp, int jbB,
                                           int lane, short8 wf[4][2])
{
#pragma unroll
    for (int s = 0; s < 4; ++s)
#pragma unroll
        for (int c = 0; c < 2; ++c)
            wf[s][c] = Wp[((jbB * 4 + s) * 2 + c) * 64 + lane];
}

// acc += sA(64x128 bf16, swizzled) @ Wf(128x32 bf16)
__device__ __forceinline__ void mfma_gemm(const unsigned short* sA, const short8 wf[4][2],
                                          f32x4 acc[4][2], int lane)
{
    const int g = lane >> 4, r = lane & 15;
#pragma unroll
    for (int s = 0; s < 4; ++s) {
        short8 a4[4];
#pragma unroll
        for (int fr = 0; fr < 4; ++fr) {
            int row = 16 * fr + r;
            int ck  = (4 * s + g) ^ (row & 7);
            a4[fr] = *(const short8*)(sA + (row << 7) + (ck << 3));
        }
#pragma unroll
        for (int fr = 0; fr < 4; ++fr)
#pragma unroll
            for (int c = 0; c < 2; ++c)
                acc[fr][c] = __builtin_amdgcn_mfma_f32_16x16x32_bf16(a4[fr], wf[s][c],
                                                                     acc[fr][c], 0, 0, 0);
    }
}

__device__ __forceinline__ void zero_acc(f32x4 acc[4][2])
{
#pragma unroll
    for (int fr = 0; fr < 4; ++fr)
#pragma unroll
        for (int c = 0; c < 2; ++c) {
            acc[fr][c][0] = 0.f; acc[fr][c][1] = 0.f;
            acc[fr][c][2] = 0.f; acc[fr][c][3] = 0.f;
        }
}

// ---------------------------------------------------------------------------
// One-time sort machinery (edge_index is layer-invariant)
__global__ __launch_bounds__(256) void hist_kernel(const int* __restrict__ col,
                                                   int* __restrict__ cnt, int E)
{
    int e = blockIdx.x * 256 + threadIdx.x;
    if (e < E) atomicAdd(&cnt[col[e]], 1);
}

__global__ __launch_bounds__(1024) void scan_kernel(const int* __restrict__ cnt,
                                                    int* __restrict__ offs, int Nn)
{
    __shared__ int ls[1024];
    int t = threadIdx.x;
    int per = (Nn + 1023) / 1024;
    int base = t * per;
    int s = 0;
    for (int k = 0; k < per; ++k) {
        int i = base + k;
        if (i < Nn) s += cnt[i];
    }
    ls[t] = s;
    __syncthreads();
    for (int d = 1; d < 1024; d <<= 1) {
        int u = (t >= d) ? ls[t - d] : 0;
        __syncthreads();
        ls[t] += u;
        __syncthreads();
    }
    int run = ls[t] - s;
    for (int k = 0; k < per; ++k) {
        int i = base + k;
        if (i < Nn) {
            offs[i] = run;
            run += cnt[i];
        }
    }
}

__global__ __launch_bounds__(256) void scatter_kernel(const int* __restrict__ row,
                                                      const int* __restrict__ col,
                                                      const int* __restrict__ offs,
                                                      int* __restrict__ tmpc,
                                                      int* __restrict__ sortedIds,
                                                      int* __restrict__ rowS,
                                                      int* __restrict__ colS, int E)
{
    int e = blockIdx.x * 256 + threadIdx.x;
    if (e < E) {
        int c = col[e];
        int p = offs[c] + atomicAdd(&tmpc[c], 1);
        sortedIds[p] = e;
        rowS[p] = row[e];
        colS[p] = c;
    }
}

// ---------------------------------------------------------------------------
// Encoder: out(bf16) = relu(X[M,16] @ W[16,128] + b)
__global__ __launch_bounds__(256) void enc_kernel(const float* __restrict__ X,
                                                  const float* __restrict__ W,
                                                  const float* __restrict__ bias,
                                                  unsigned short* __restrict__ out, int M)
{
    __shared__ float sW[F_IN * H];
    __shared__ float sb[H];
    int t = threadIdx.x;
    reinterpret_cast<float4*>(sW)[t]       = reinterpret_cast<const float4*>(W)[t];
    reinterpret_cast<float4*>(sW)[t + 256] = reinterpret_cast<const float4*>(W)[t + 256];
    if (t < H) sb[t] = bias[t];
    __syncthreads();
    int row = blockIdx.x * 2 + (t >> 7);
    if (row >= M) return;
    int j = t & 127;
    float acc = sb[j];
#pragma unroll
    for (int k = 0; k < F_IN; ++k)
        acc += X[(size_t)row * F_IN + k] * sW[k * H + j];
    out[(size_t)row * H + j] = f2bf(fmaxf(acc, 0.f));
}

// Gather-encoder: out[p](bf16) = relu(X[sortedIds[p],16] @ W + b)
__global__ __launch_bounds__(256) void enc_gather_kernel(const float* __restrict__ X,
                                                         const int* __restrict__ sortedIds,
                                                         const float* __restrict__ W,
                                                         const float* __restrict__ bias,
                                                         unsigned short* __restrict__ out,
                                                         int M)
{
    __shared__ float sW[F_IN * H];
    __shared__ float sb[H];
    int t = threadIdx.x;
    reinterpret_cast<float4*>(sW)[t]       = reinterpret_cast<const float4*>(W)[t];
    reinterpret_cast<float4*>(sW)[t + 256] = reinterpret_cast<const float4*>(W)[t + 256];
    if (t < H) sb[t] = bias[t];
    __syncthreads();
    int p = blockIdx.x * 2 + (t >> 7);
    if (p >= M) return;
    int src = sortedIds[p];
    int j = t & 127;
    float acc = sb[j];
#pragma unroll
    for (int k = 0; k < F_IN; ++k)
        acc += X[(size_t)src * F_IN + k] * sW[k * H + j];
    out[(size_t)p * H + j] = f2bf(fmaxf(acc, 0.f));
}

// ---------------------------------------------------------------------------
// B precompute: B(bf16) = bn(h) @ W2. Block 0 also zeroes this layer's stats.
__global__ __launch_bounds__(256, 8) void bk_kernel(const unsigned short* __restrict__ hb,
                                                    const short8* __restrict__ W2p,
                                                    unsigned short* __restrict__ Bout, int M,
                                                    const float* __restrict__ Sh,
                                                    const float* __restrict__ gh,
                                                    const float* __restrict__ bh,
                                                    float invN,
                                                    float* __restrict__ Szero)
{
    __shared__ __align__(16) unsigned short sA[64 * 128];
    __shared__ float bnp[256];
    const int t = threadIdx.x, lane = t & 63, w = t >> 6, jb = 32 * w;
    const int r0 = blockIdx.x * 64;
    if (blockIdx.x == 0) {            // zero stats for this layer (512 floats)
        Szero[t] = 0.f;
        Szero[t + 256] = 0.f;
    }
    if (t < 128) bn_param(Sh, gh, bh, invN, t, bnp, bnp + 128);
    __syncthreads();
    stage_aff(hb, sA, r0, M, t, bnp, bnp + 128);
    const int g = lane >> 4, c0 = lane & 15;
    short8 wf[4][2];
    load_wfrag(W2p, w, lane, wf);
    f32x4 acc[4][2];
    zero_acc(acc);
    __syncthreads();
    mfma_gemm(sA, wf, acc, lane);
#pragma unroll
    for (int fr = 0; fr < 4; ++fr)
#pragma unroll
        for (int c = 0; c < 2; ++c) {
            int j = jb + 16 * c + c0;
#pragma unroll
            for (int r = 0; r < 4; ++r) {
                int row = r0 + 16 * fr + 4 * g + r;
                if (row < M) Bout[(size_t)row * H + j] = f2bf(acc[fr][c][r]);
            }
        }
}

// ---------------------------------------------------------------------------
// Fused edge kernel (bf16 e col-sorted; BN applied at staging):
//   e'[p] = relu(bn_e(e[p])@W3 + bn_h(h[rowS])@W1 + B[colS] + be)
//   m     = relu(e'@U2 + bn_h(h[rowS])@U1 + b1)
//   aggsum[col] += segment-MEAN partials ; fused e'-stats
__global__ __launch_bounds__(256, 4) void edge_kernel(unsigned short* eb,
                                                      const int* __restrict__ rowS,
                                                      const int* __restrict__ colS,
                                                      const int* __restrict__ cnt,
                                                      const unsigned short* __restrict__ hb,
                                                      const unsigned short* __restrict__ Bsrc,
                                                      const short8* __restrict__ wfrL,
                                                      const float* __restrict__ be,
                                                      const float* __restrict__ b1,
                                                      float* __restrict__ aggsum, int E,
                                                      const float* __restrict__ Sh,
                                                      const float* __restrict__ gh,
                                                      const float* __restrict__ bh,
                                                      float invN,
                                                      const float* __restrict__ Se,
                                                      const float* __restrict__ ge,
                                                      const float* __restrict__ beB,
                                                      float invE,
                                                      float* __restrict__ eStats)
{
    __shared__ __align__(16) unsigned char smem[64 * 128 * 4 + 256 + 256 + 2048];
    unsigned short* sE  = (unsigned short*)smem;          // 16 KB  e (bf16)
    unsigned short* sHt = sE + 64 * 128;                  // 16 KB  h[row] (bf16)
    float*          mbuf = (float*)smem;                  // 32 KB overlay (post-GEMM2)
    int*            scol = (int*)(smem + 64 * 128 * 4);          // 256 B
    float*          sinv = (float*)(smem + 64 * 128 * 4 + 256);  // 256 B
    float*          bnp  = (float*)(smem + 64 * 128 * 4 + 512);  // 2 KB

    const int t = threadIdx.x, lane = t & 63, w = t >> 6, jb = 32 * w;
    const int e0 = blockIdx.x * 64;
    const int g = lane >> 4, c0 = lane & 15;

    if (t < 64) {
        int cc = colS[(e0 + t < E) ? (e0 + t) : (E - 1)];
        scol[t] = cc;
        int c = cnt[cc];
        sinv[t] = 1.f / (float)(c > 1 ? c : 1);
    }
    if (t < 128) bn_param(Sh, gh, bh, invN, t, bnp, bnp + 128);
    else         bn_param(Se, ge, beB, invE, t - 128, bnp + 256, bnp + 384);

    // per-lane col indices + early B prefetch (bf16, no LDS dependency)
    int cidx[4][4];
#pragma unroll
    for (int fr = 0; fr < 4; ++fr)
#pragma unroll
        for (int r = 0; r < 4; ++r) {
            int p  = e0 + 16 * fr + 4 * g + r;
            int pc = (p < E) ? p : (E - 1);
            cidx[fr][r] = colS[pc];
        }
    unsigned short bPre[4][2][4];
#pragma unroll
    for (int fr = 0; fr < 4; ++fr)
#pragma unroll
        for (int c = 0; c < 2; ++c)
#pragma unroll
            for (int r = 0; r < 4; ++r)
                bPre[fr][c][r] = Bsrc[(size_t)cidx[fr][r] * H + jb + 16 * c + c0];

    __syncthreads();   // bnp ready
    stage_aff(eb, sE, e0, E, t, bnp + 256, bnp + 384);
    stage_aff_gather(hb, rowS, sHt, e0, E, t, bnp, bnp + 128);

    short8 wf[4][2];
    f32x4 acc[4][2];
    zero_acc(acc);
    load_wfrag(wfrL + 2 * 2048, w, lane, wf);   // W3
    __syncthreads();
    mfma_gemm(sE, wf, acc, lane);
    load_wfrag(wfrL + 0 * 2048, w, lane, wf);   // W1
    mfma_gemm(sHt, wf, acc, lane);
    __syncthreads();   // all reads of sE done -> safe to overwrite with e'

    // epilogue 1: e' = relu(acc + B[col] + be) -> bf16 global + back to sE
    float s1[2] = {0.f, 0.f}, s2[2] = {0.f, 0.f};
#pragma unroll
    for (int fr = 0; fr < 4; ++fr)
#pragma unroll
        for (int c = 0; c < 2; ++c) {
            int j = jb + 16 * c + c0;
            float bej = be[j];
#pragma unroll
            for (int r = 0; r < 4; ++r) {
                int Rl = 16 * fr + 4 * g + r;
                int p  = e0 + Rl;
                float v = acc[fr][c][r] + bf2f(bPre[fr][c][r]) + bej;
                v = fmaxf(v, 0.f);
                unsigned short vb = f2bf(v);
                if (p < E) {
                    eb[(size_t)p * H + j] = vb;
                    s1[c] += v;
                    s2[c] += v * v;
                }
                sE[(Rl << 7) + (j ^ ((Rl & 7) << 3))] = vb;
            }
        }
    __syncthreads();

    // GEMM2: m = e'@U2 + bn_h(h[rowS])@U1
    zero_acc(acc);
    load_wfrag(wfrL + 4 * 2048, w, lane, wf);   // U2
    mfma_gemm(sE, wf, acc, lane);
    load_wfrag(wfrL + 3 * 2048, w, lane, wf);   // U1
    mfma_gemm(sHt, wf, acc, lane);
    __syncthreads();   // all GEMM2 LDS reads done -> mbuf overlay safe

    // epilogue 2: m -> mbuf (swizzled)
#pragma unroll
    for (int fr = 0; fr < 4; ++fr)
#pragma unroll
        for (int c = 0; c < 2; ++c) {
            int j = jb + 16 * c + c0;
            float b1j = b1[j];
#pragma unroll
            for (int r = 0; r < 4; ++r) {
                int Rl = 16 * fr + 4 * g + r;
                float v = fmaxf(acc[fr][c][r] + b1j, 0.f);
                mbuf[(Rl << 7) + (j ^ (((Rl >> 2) & 3) << 3))] = v;
            }
        }
    __syncthreads();

    // segmented reduction, 2-way parallel over row halves:
    // thread (j = t&127, half = t>>7) walks rows [32*half, 32*half+32),
    // emitting mean-scaled partials (run * 1/cnt) per segment.
    {
        int j = t & 127, half = t >> 7;
        int rbeg = half * 32, rend = rbeg + 32;
        int rlim = E - e0;   // rows >= rlim are tail padding
        float run = 0.f;
        int cur = scol[rbeg];
        for (int row = rbeg; row < rend; ++row) {
            int cc = scol[row];
            float v = mbuf[(row << 7) + (j ^ (((row >> 2) & 3) << 3))];
            if (cc != cur) {
                if (run != 0.f)
                    atomicAdd(&aggsum[(size_t)cur * H + j], run * sinv[row - 1]);
                run = 0.f;
                cur = cc;
            }
            if (row < rlim) run += v;
        }
        if (run != 0.f)
            atomicAdd(&aggsum[(size_t)cur * H + j], run * sinv[rend - 1]);
    }

    // fused e'-stats
#pragma unroll
    for (int c = 0; c < 2; ++c) {
        float a = s1[c], b = s2[c];
        a += __shfl_xor(a, 16); a += __shfl_xor(a, 32);
        b += __shfl_xor(b, 16); b += __shfl_xor(b, 32);
        if (g == 0) {
            int j = jb + 16 * c + c0;
            atomicAdd(&eStats[j], a);
            atomicAdd(&eStats[H + j], b);
        }
    }
}

// ---------------------------------------------------------------------------
// Node update (in place, bf16 h): h = relu(bn_h(h)@V1 + aggmean@V2 + b2);
// fused h-stats; zeroes its aggsum rows for the next layer.
__global__ __launch_bounds__(256, 8) void node_kernel(unsigned short* hb,
                                                      float* __restrict__ aggsum,
                                                      const short8* __restrict__ wfrL,
                                                      const float* __restrict__ b2, int M,
                                                      const float* __restrict__ Sh,
                                                      const float* __restrict__ gh,
                                                      const float* __restrict__ bh,
                                                      float invN,
                                                      float* __restrict__ hStats)
{
    __shared__ __align__(16) unsigned short sA[64 * 128];
    __shared__ float bnp[256];
    const int t = threadIdx.x, lane = t & 63, w = t >> 6, jb = 32 * w;
    const int r0 = blockIdx.x * 64;
    if (t < 128) bn_param(Sh, gh, bh, invN, t, bnp, bnp + 128);
    __syncthreads();
    stage_aff(hb, sA, r0, M, t, bnp, bnp + 128);
    short8 wf[4][2];
    load_wfrag(wfrL + 5 * 2048, w, lane, wf);   // V1
    f32x4 acc[4][2];
    zero_acc(acc);
    __syncthreads();
    mfma_gemm(sA, wf, acc, lane);
    __syncthreads();   // h-tile reads done
    stage_agg_bf16(aggsum, sA, r0, M, t);
    // zero the aggsum rows this block consumed (next layer starts from 0)
#pragma unroll
    for (int i = 0; i < 4; ++i) {
        int cid = t + 256 * i;
        int row = cid >> 4, ck = cid & 15, grow = r0 + row;
        if (grow < M) {
            float4* q = (float4*)(aggsum + (size_t)grow * H + ck * 8);
            q[0] = make_float4(0.f, 0.f, 0.f, 0.f);
            q[1] = make_float4(0.f, 0.f, 0.f, 0.f);
        }
    }
    load_wfrag(wfrL + 6 * 2048, w, lane, wf);   // V2
    __syncthreads();
    mfma_gemm(sA, wf, acc, lane);
    const int g = lane >> 4, c0 = lane & 15;
    float s1[2] = {0.f, 0.f}, s2[2] = {0.f, 0.f};
#pragma unroll
    for (int fr = 0; fr < 4; ++fr)
#pragma unroll
        for (int c = 0; c < 2; ++c) {
            int j = jb + 16 * c + c0;
            float bj = b2[j];
#pragma unroll
            for (int r = 0; r < 4; ++r) {
                int row = r0 + 16 * fr + 4 * g + r;
                if (row < M) {
                    float v = fmaxf(acc[fr][c][r] + bj, 0.f);
                    hb[(size_t)row * H + j] = f2bf(v);
                    s1[c] += v;
                    s2[c] += v * v;
                }
            }
        }
#pragma unroll
    for (int c = 0; c < 2; ++c) {
        float a = s1[c], b = s2[c];
        a += __shfl_xor(a, 16); a += __shfl_xor(a, 32);
        b += __shfl_xor(b, 16); b += __shfl_xor(b, 32);
        if (g == 0) {
            int j = jb + 16 * c + c0;
            atomicAdd(&hStats[j], a);
            atomicAdd(&hStats[H + j], b);
        }
    }
}

// ---------------------------------------------------------------------------
// Final readout: out = [mean(h) | mean(e)] @ reg_w + reg_b
__global__ __launch_bounds__(256) void final_kernel(const float* __restrict__ hsum,
                                                    const float* __restrict__ esum,
                                                    const float* __restrict__ reg_w,
                                                    const float* __restrict__ reg_b,
                                                    float* __restrict__ out,
                                                    float invN, float invE)
{
    __shared__ float red[256];
    int t = threadIdx.x;
    float v = (t < 128) ? hsum[t] * invN * reg_w[t]
                        : esum[t - 128] * invE * reg_w[t];
    red[t] = v;
    __syncthreads();
    for (int s = 128; s > 0; s >>= 1) {
        if (t < s) red[t] += red[t + s];
        __syncthreads();
    }
    if (t == 0) out[0] = red[0] + reg_b[0];
}

// ---------------------------------------------------------------------------
extern "C" void kernel_launch(void* const* d_in, const int* in_sizes, int n_in,
                              void* d_out, int out_size, void* d_ws, size_t ws_size,
                              hipStream_t stream)
{
    const float* x          = (const float*)d_in[0];
    const int*   edge_index = (const int*)  d_in[1];
    const float* edge_attr  = (const float*)d_in[2];
    const float* enc_node_w = (const float*)d_in[3];
    const float* enc_node_b = (const float*)d_in[4];
    const float* enc_edge_w = (const float*)d_in[5];
    const float* enc_edge_b = (const float*)d_in[6];
    const float* edge_w     = (const float*)d_in[7];
    const float* edge_b     = (const float*)d_in[8];
    const float* n1_w       = (const float*)d_in[9];
    const float* n1_b       = (const float*)d_in[10];
    const float* n2_w       = (const float*)d_in[11];
    const float* n2_b       = (const float*)d_in[12];
    const float* bn_node_g  = (const float*)d_in[13];
    const float* bn_node_b  = (const float*)d_in[14];
    const float* bn_edge_g  = (const float*)d_in[15];
    const float* bn_edge_b  = (const float*)d_in[16];
    const float* reg_w      = (const float*)d_in[17];
    const float* reg_b      = (const float*)d_in[18];

    const int N = in_sizes[0] / F_IN;
    const int E = in_sizes[1] / 2;
    const size_t NH = (size_t)N * H;
    const size_t EH = (size_t)E * H;

    float* ws     = (float*)d_ws;
    float* aggsum = ws;                 // [N,128] f32 (zeroed once; node re-zeroes)
    float* statsA = aggsum + NH;        // 512
    float* statsB = statsA + 512;       // 512
    short8* wfr   = (short8*)(statsB + 512);        // 21*2048 short8 = 672 KB
    unsigned short* hbuf = (unsigned short*)(wfr + 21 * 2048);  // [N,128] bf16
    unsigned short* ebuf = hbuf + NH;                           // [E,128] bf16 (col-sorted)
    unsigned short* Bbuf = ebuf + EH;                           // [N,128] bf16
    int*   cnt_i  = (int*)(Bbuf + NH);      // [N]
    int*   tmpc   = cnt_i + N;              // [N]
    int*   offs   = tmpc + N;               // [N+1]
    int*   sortedIds = offs + N + 1;        // [E]
    int*   rowS   = sortedIds + E;          // [E]
    int*   colS   = rowS + E;               // [E]

    const int* row_idx = edge_index;
    const int* col_idx = edge_index + E;
    const float invN = 1.f / (float)N;
    const float invE = 1.f / (float)E;

    // one-time: sort edges by col; bf16 weight fragments; encoders
    (void)hipMemsetAsync(cnt_i, 0, (size_t)2 * N * sizeof(int), stream);
    (void)hipMemsetAsync(aggsum, 0, NH * sizeof(float), stream);
    hist_kernel<<<(E + 255) / 256, 256, 0, stream>>>(col_idx, cnt_i, E);
    scan_kernel<<<1, 1024, 0, stream>>>(cnt_i, offs, N);
    scatter_kernel<<<(E + 255) / 256, 256, 0, stream>>>(row_idx, col_idx, offs, tmpc,
                                                        sortedIds, rowS, colS, E);
    wbf16_kernel<<<21, 256, 0, stream>>>(edge_w, n1_w, n2_w, wfr);

    enc_kernel<<<(N + 1) / 2, 256, 0, stream>>>(x, enc_node_w, enc_node_b, hbuf, N);
    enc_gather_kernel<<<(E + 1) / 2, 256, 0, stream>>>(edge_attr, sortedIds,
                                                       enc_edge_w, enc_edge_b, ebuf, E);

    const int nodeBlocks = (N + 63) / 64;
    const int edgeBlocks = (E + 63) / 64;

    for (int i = 0; i < 3; ++i) {
        float*       Scur  = (i & 1) ? statsB : statsA;
        const float* Sprev = (i == 0) ? nullptr : ((i & 1) ? statsA : statsB);
        const float* Sh = Sprev;
        const float* Se = Sprev ? Sprev + 256 : nullptr;
        const short8* wfrL = wfr + (size_t)i * 7 * 2048;
        bk_kernel<<<nodeBlocks, 256, 0, stream>>>(
            hbuf, wfrL + 1 * 2048, Bbuf, N, Sh, bn_node_g, bn_node_b, invN, Scur);
        edge_kernel<<<edgeBlocks, 256, 0, stream>>>(
            ebuf, rowS, colS, cnt_i, hbuf, Bbuf, wfrL,
            edge_b + i * H, n1_b + i * H,
            aggsum, E,
            Sh, bn_node_g, bn_node_b, invN,
            Se, bn_edge_g, bn_edge_b, invE,
            Scur + 256);
        node_kernel<<<nodeBlocks, 256, 0, stream>>>(
            hbuf, aggsum, wfrL, n2_b + i * H, N,
            Sh, bn_node_g, bn_node_b, invN,
            Scur);
    }
    // i=2 wrote statsA
    final_kernel<<<1, 256, 0, stream>>>(statsA, statsA + 256, reg_w, reg_b,
                                        (float*)d_out, invN, invE);
}

// Round 17
// 798.166 us; speedup vs baseline: 1.1244x; 1.0210x over previous
//
#include <hip/hip_runtime.h>

#define H 128
#define F_IN 16
#define BNEPS 1e-5f

typedef __attribute__((ext_vector_type(8))) short short8;
typedef __attribute__((ext_vector_type(4))) float f32x4;

// f32 -> bf16 round-to-nearest-even
__device__ __forceinline__ unsigned short f2bf(float f)
{
    unsigned u = __builtin_bit_cast(unsigned, f);
    u += 0x7FFFu + ((u >> 16) & 1u);
    return (unsigned short)(u >> 16);
}
__device__ __forceinline__ float bf2f(unsigned short h)
{
    return __builtin_bit_cast(float, (unsigned)h << 16);
}

// BN affine params for feature j into LDS: s[j], t[j] (identity if S==nullptr)
__device__ __forceinline__ void bn_param(const float* __restrict__ S,
                                         const float* __restrict__ g,
                                         const float* __restrict__ b,
                                         float invM, int j,
                                         float* __restrict__ sS, float* __restrict__ sT)
{
    float s = 1.f, tt = 0.f;
    if (S) {
        float mean = S[j] * invM;
        float var  = S[H + j] * invM - mean * mean;
        s  = rsqrtf(var + BNEPS) * g[j];
        tt = b[j] - mean * s;
    }
    sS[j] = s;
    sT[j] = tt;
}

// ---------------------------------------------------------------------------
// Stage a 64x128 bf16 tile with per-feature affine (s,t from LDS) into
// swizzled LDS. element (row,k) -> ushort idx row*128 + (k ^ ((row&7)<<3))
__device__ __forceinline__ void stage_aff(const unsigned short* __restrict__ src,
                                          unsigned short* sA, int r0, int M, int t,
                                          const float* __restrict__ sS,
                                          const float* __restrict__ sT)
{
#pragma unroll
    for (int i = 0; i < 4; ++i) {
        int cid  = t + 256 * i;
        int row  = cid >> 4;
        int ck   = cid & 15;
        int grow = r0 + row;
        short8 v = (short8)0;
        if (grow < M) {
            v = *(const short8*)(src + (size_t)grow * H + ck * 8);
            int j0 = ck * 8;
#pragma unroll
            for (int j = 0; j < 8; ++j)
                v[j] = (short)f2bf(bf2f((unsigned short)v[j]) * sS[j0 + j] + sT[j0 + j]);
        }
        *(short8*)(sA + (row << 7) + ((ck ^ (row & 7)) << 3)) = v;
    }
}

// Gather variant: tile row i holds src[idx[p0+i]], same affine.
__device__ __forceinline__ void stage_aff_gather(const unsigned short* __restrict__ src,
                                                 const int* __restrict__ idx,
                                                 unsigned short* sA, int p0, int M, int t,
                                                 const float* __restrict__ sS,
                                                 const float* __restrict__ sT)
{
#pragma unroll
    for (int i = 0; i < 4; ++i) {
        int cid = t + 256 * i;
        int row = cid >> 4;
        int ck  = cid & 15;
        int p   = p0 + row;
        short8 v = (short8)0;
        if (p < M) {
            v = *(const short8*)(src + (size_t)idx[p] * H + ck * 8);
            int j0 = ck * 8;
#pragma unroll
            for (int j = 0; j < 8; ++j)
                v[j] = (short)f2bf(bf2f((unsigned short)v[j]) * sS[j0 + j] + sT[j0 + j]);
        }
        *(short8*)(sA + (row << 7) + ((ck ^ (row & 7)) << 3)) = v;
    }
}

// aggsum already holds per-node MEANS -> just convert to bf16; then zero rows
__device__ __forceinline__ void stage_agg_bf16(float* __restrict__ aggsum,
                                               unsigned short* sA, int r0, int M, int t)
{
#pragma unroll
    for (int i = 0; i < 4; ++i) {
        int cid  = t + 256 * i;
        int row  = cid >> 4;
        int ck   = cid & 15;
        int grow = r0 + row;
        short8 ph = (short8)0;
        if (grow < M) {
            float4* q = (float4*)(aggsum + (size_t)grow * H + ck * 8);
            float4 a = q[0], b = q[1];
            float xs[8] = {a.x, a.y, a.z, a.w, b.x, b.y, b.z, b.w};
#pragma unroll
            for (int j = 0; j < 8; ++j) ph[j] = (short)f2bf(xs[j]);
            q[0] = make_float4(0.f, 0.f, 0.f, 0.f);   // zero for next layer
            q[1] = make_float4(0.f, 0.f, 0.f, 0.f);
        }
        *(short8*)(sA + (row << 7) + ((ck ^ (row & 7)) << 3)) = ph;
    }
}

// ---------------------------------------------------------------------------
// One-time weight bf16 fragment precompute (21 matrices, unscaled).
__global__ __launch_bounds__(256) void wbf16_kernel(const float* __restrict__ edge_w,
                                                    const float* __restrict__ n1_w,
                                                    const float* __restrict__ n2_w,
                                                    short8* __restrict__ out)
{
    int m = blockIdx.x;
    int layer = m / 7, k = m % 7;
    const float* W = (k < 3) ? edge_w + (size_t)layer * 384 * H + (size_t)k * H * H
                   : (k < 5) ? n1_w + (size_t)layer * 256 * H + (size_t)(k - 3) * H * H
                             : n2_w + (size_t)layer * 256 * H + (size_t)(k - 5) * H * H;
    short8* oh = out + (size_t)m * 2048;
    for (int e = threadIdx.x; e < 2048; e += 256) {
        int jbB = e >> 9, s = (e >> 7) & 3, c = (e >> 6) & 1, lane = e & 63;
        int g = lane >> 4, c0 = lane & 15;
        short8 hi;
#pragma unroll
        for (int j = 0; j < 8; ++j)
            hi[j] = (short)f2bf(W[(size_t)(32 * s + 8 * g + j) * H + jbB * 32 + 16 * c + c0]);
        oh[e] = hi;
    }
}

// Load precomputed bf16 fragments: 8 coalesced 16B loads.
__device__ __forceinline__ void load_wfrag(const short8* __restrict__ Wp, int jbB,
                                           int lane, short8 wf[4][2])
{
#pragma unroll
    for (int s = 0; s < 4; ++s)
#pragma unroll
        for (int c = 0; c < 2; ++c)
            wf[s][c] = Wp[((jbB * 4 + s) * 2 + c) * 64 + lane];
}

// acc += sA(64x128 bf16, swizzled) @ Wf(128x32 bf16)
__device__ __forceinline__ void mfma_gemm(const unsigned short* sA, const short8 wf[4][2],
                                          f32x4 acc[4][2], int lane)
{
    const int g = lane >> 4, r = lane & 15;
#pragma unroll
    for (int s = 0; s < 4; ++s) {
        short8 a4[4];
#pragma unroll
        for (int fr = 0; fr < 4; ++fr) {
            int row = 16 * fr + r;
            int ck  = (4 * s + g) ^ (row & 7);
            a4[fr] = *(const short8*)(sA + (row << 7) + (ck << 3));
        }
#pragma unroll
        for (int fr = 0; fr < 4; ++fr)
#pragma unroll
            for (int c = 0; c < 2; ++c)
                acc[fr][c] = __builtin_amdgcn_mfma_f32_16x16x32_bf16(a4[fr], wf[s][c],
                                                                     acc[fr][c], 0, 0, 0);
    }
}

__device__ __forceinline__ void zero_acc(f32x4 acc[4][2])
{
#pragma unroll
    for (int fr = 0; fr < 4; ++fr)
#pragma unroll
        for (int c = 0; c < 2; ++c) {
            acc[fr][c][0] = 0.f; acc[fr][c][1] = 0.f;
            acc[fr][c][2] = 0.f; acc[fr][c][3] = 0.f;
        }
}

// ---------------------------------------------------------------------------
// One-time sort machinery (edge_index is layer-invariant)
__global__ __launch_bounds__(256) void hist_kernel(const int* __restrict__ col,
                                                   int* __restrict__ cnt, int E)
{
    int e = blockIdx.x * 256 + threadIdx.x;
    if (e < E) atomicAdd(&cnt[col[e]], 1);
}

__global__ __launch_bounds__(1024) void scan_kernel(const int* __restrict__ cnt,
                                                    int* __restrict__ offs, int Nn)
{
    __shared__ int ls[1024];
    int t = threadIdx.x;
    int per = (Nn + 1023) / 1024;
    int base = t * per;
    int s = 0;
    for (int k = 0; k < per; ++k) {
        int i = base + k;
        if (i < Nn) s += cnt[i];
    }
    ls[t] = s;
    __syncthreads();
    for (int d = 1; d < 1024; d <<= 1) {
        int u = (t >= d) ? ls[t - d] : 0;
        __syncthreads();
        ls[t] += u;
        __syncthreads();
    }
    int run = ls[t] - s;
    for (int k = 0; k < per; ++k) {
        int i = base + k;
        if (i < Nn) {
            offs[i] = run;
            run += cnt[i];
        }
    }
}

__global__ __launch_bounds__(256) void scatter_kernel(const int* __restrict__ row,
                                                      const int* __restrict__ col,
                                                      const int* __restrict__ offs,
                                                      int* __restrict__ tmpc,
                                                      int* __restrict__ sortedIds,
                                                      int* __restrict__ rowS,
                                                      int* __restrict__ colS, int E)
{
    int e = blockIdx.x * 256 + threadIdx.x;
    if (e < E) {
        int c = col[e];
        int p = offs[c] + atomicAdd(&tmpc[c], 1);
        sortedIds[p] = e;
        rowS[p] = row[e];
        colS[p] = c;
    }
}

// ---------------------------------------------------------------------------
// Encoder: out(bf16) = relu(X[M,16] @ W[16,128] + b)
__global__ __launch_bounds__(256) void enc_kernel(const float* __restrict__ X,
                                                  const float* __restrict__ W,
                                                  const float* __restrict__ bias,
                                                  unsigned short* __restrict__ out, int M)
{
    __shared__ float sW[F_IN * H];
    __shared__ float sb[H];
    int t = threadIdx.x;
    reinterpret_cast<float4*>(sW)[t]       = reinterpret_cast<const float4*>(W)[t];
    reinterpret_cast<float4*>(sW)[t + 256] = reinterpret_cast<const float4*>(W)[t + 256];
    if (t < H) sb[t] = bias[t];
    __syncthreads();
    int row = blockIdx.x * 2 + (t >> 7);
    if (row >= M) return;
    int j = t & 127;
    float acc = sb[j];
#pragma unroll
    for (int k = 0; k < F_IN; ++k)
        acc += X[(size_t)row * F_IN + k] * sW[k * H + j];
    out[(size_t)row * H + j] = f2bf(fmaxf(acc, 0.f));
}

// Gather-encoder: out[p](bf16) = relu(X[sortedIds[p],16] @ W + b)
__global__ __launch_bounds__(256) void enc_gather_kernel(const float* __restrict__ X,
                                                         const int* __restrict__ sortedIds,
                                                         const float* __restrict__ W,
                                                         const float* __restrict__ bias,
                                                         unsigned short* __restrict__ out,
                                                         int M)
{
    __shared__ float sW[F_IN * H];
    __shared__ float sb[H];
    int t = threadIdx.x;
    reinterpret_cast<float4*>(sW)[t]       = reinterpret_cast<const float4*>(W)[t];
    reinterpret_cast<float4*>(sW)[t + 256] = reinterpret_cast<const float4*>(W)[t + 256];
    if (t < H) sb[t] = bias[t];
    __syncthreads();
    int p = blockIdx.x * 2 + (t >> 7);
    if (p >= M) return;
    int src = sortedIds[p];
    int j = t & 127;
    float acc = sb[j];
#pragma unroll
    for (int k = 0; k < F_IN; ++k)
        acc += X[(size_t)src * F_IN + k] * sW[k * H + j];
    out[(size_t)p * H + j] = f2bf(fmaxf(acc, 0.f));
}

// ---------------------------------------------------------------------------
// Fused edge kernel (bf16 e col-sorted; BN at staging; B computed in-kernel):
//   e'[p] = relu(bn_e(e[p])@W3 + bn_h(h[rowS])@W1 + bn_h(h[colS])@W2 + be)
//   m     = relu(e'@U2 + bn_h(h[rowS])@U1 + b1)
//   aggsum[col] += segment-MEAN partials ; fused e'-stats
__global__ __launch_bounds__(256, 3) void edge_kernel(unsigned short* eb,
                                                      const int* __restrict__ rowS,
                                                      const int* __restrict__ colS,
                                                      const int* __restrict__ cnt,
                                                      const unsigned short* __restrict__ hb,
                                                      const short8* __restrict__ wfrL,
                                                      const float* __restrict__ be,
                                                      const float* __restrict__ b1,
                                                      float* __restrict__ aggsum, int E,
                                                      const float* __restrict__ Sh,
                                                      const float* __restrict__ gh,
                                                      const float* __restrict__ bh,
                                                      float invN,
                                                      const float* __restrict__ Se,
                                                      const float* __restrict__ ge,
                                                      const float* __restrict__ beB,
                                                      float invE,
                                                      float* __restrict__ eStats)
{
    __shared__ __align__(16) unsigned char smem[64 * 128 * 6 + 256 + 256 + 2048];
    unsigned short* sE  = (unsigned short*)smem;          // 16 KB  e (bf16)
    unsigned short* sHt = sE + 64 * 128;                  // 16 KB  h[rowS] (bf16)
    unsigned short* sHc = sHt + 64 * 128;                 // 16 KB  h[colS] (bf16)
    float*          mbuf = (float*)smem;                  // 32 KB overlay sE+sHt (post-GEMM2)
    int*            scol = (int*)(smem + 64 * 128 * 6);          // 256 B
    float*          sinv = (float*)(smem + 64 * 128 * 6 + 256);  // 256 B
    float*          bnp  = (float*)(smem + 64 * 128 * 6 + 512);  // 2 KB

    const int t = threadIdx.x, lane = t & 63, w = t >> 6, jb = 32 * w;
    const int e0 = blockIdx.x * 64;
    const int g = lane >> 4, c0 = lane & 15;

    if (t < 64) {
        int cc = colS[(e0 + t < E) ? (e0 + t) : (E - 1)];
        scol[t] = cc;
        int c = cnt[cc];
        sinv[t] = 1.f / (float)(c > 1 ? c : 1);
    }
    if (t < 128) bn_param(Sh, gh, bh, invN, t, bnp, bnp + 128);
    else         bn_param(Se, ge, beB, invE, t - 128, bnp + 256, bnp + 384);
    __syncthreads();   // bnp + scol ready

    stage_aff(eb, sE, e0, E, t, bnp + 256, bnp + 384);
    stage_aff_gather(hb, rowS, sHt, e0, E, t, bnp, bnp + 128);
    stage_aff_gather(hb, scol - 0, sHc, 0, E - e0 > 64 ? 64 : (E - e0), t, bnp, bnp + 128);
    // note: scol holds cols for rows 0..63 of this tile; p0=0 with M=rows-in-tile

    short8 wf[4][2];
    f32x4 acc[4][2];
    zero_acc(acc);
    load_wfrag(wfrL + 2 * 2048, w, lane, wf);   // W3
    __syncthreads();
    mfma_gemm(sE, wf, acc, lane);
    load_wfrag(wfrL + 0 * 2048, w, lane, wf);   // W1
    mfma_gemm(sHt, wf, acc, lane);
    load_wfrag(wfrL + 1 * 2048, w, lane, wf);   // W2 (B-term, in-kernel)
    mfma_gemm(sHc, wf, acc, lane);
    __syncthreads();   // all reads of sE done -> safe to overwrite with e'

    // epilogue 1: e' = relu(acc + be) -> bf16 global + back to sE
    float s1[2] = {0.f, 0.f}, s2[2] = {0.f, 0.f};
#pragma unroll
    for (int fr = 0; fr < 4; ++fr)
#pragma unroll
        for (int c = 0; c < 2; ++c) {
            int j = jb + 16 * c + c0;
            float bej = be[j];
#pragma unroll
            for (int r = 0; r < 4; ++r) {
                int Rl = 16 * fr + 4 * g + r;
                int p  = e0 + Rl;
                float v = acc[fr][c][r] + bej;
                v = fmaxf(v, 0.f);
                unsigned short vb = f2bf(v);
                if (p < E) {
                    eb[(size_t)p * H + j] = vb;
                    s1[c] += v;
                    s2[c] += v * v;
                }
                sE[(Rl << 7) + (j ^ ((Rl & 7) << 3))] = vb;
            }
        }
    __syncthreads();

    // GEMM2: m = e'@U2 + bn_h(h[rowS])@U1
    zero_acc(acc);
    load_wfrag(wfrL + 4 * 2048, w, lane, wf);   // U2
    mfma_gemm(sE, wf, acc, lane);
    load_wfrag(wfrL + 3 * 2048, w, lane, wf);   // U1
    mfma_gemm(sHt, wf, acc, lane);
    __syncthreads();   // all GEMM2 LDS reads done -> mbuf overlay safe

    // epilogue 2: m -> mbuf (swizzled)
#pragma unroll
    for (int fr = 0; fr < 4; ++fr)
#pragma unroll
        for (int c = 0; c < 2; ++c) {
            int j = jb + 16 * c + c0;
            float b1j = b1[j];
#pragma unroll
            for (int r = 0; r < 4; ++r) {
                int Rl = 16 * fr + 4 * g + r;
                float v = fmaxf(acc[fr][c][r] + b1j, 0.f);
                mbuf[(Rl << 7) + (j ^ (((Rl >> 2) & 3) << 3))] = v;
            }
        }
    __syncthreads();

    // segmented reduction, 2-way parallel over row halves, emitting mean partials
    {
        int j = t & 127, half = t >> 7;
        int rbeg = half * 32, rend = rbeg + 32;
        int rlim = E - e0;   // rows >= rlim are tail padding
        float run = 0.f;
        int cur = scol[rbeg];
        for (int row = rbeg; row < rend; ++row) {
            int cc = scol[row];
            float v = mbuf[(row << 7) + (j ^ (((row >> 2) & 3) << 3))];
            if (cc != cur) {
                if (run != 0.f)
                    atomicAdd(&aggsum[(size_t)cur * H + j], run * sinv[row - 1]);
                run = 0.f;
                cur = cc;
            }
            if (row < rlim) run += v;
        }
        if (run != 0.f)
            atomicAdd(&aggsum[(size_t)cur * H + j], run * sinv[rend - 1]);
    }

    // fused e'-stats
#pragma unroll
    for (int c = 0; c < 2; ++c) {
        float a = s1[c], b = s2[c];
        a += __shfl_xor(a, 16); a += __shfl_xor(a, 32);
        b += __shfl_xor(b, 16); b += __shfl_xor(b, 32);
        if (g == 0) {
            int j = jb + 16 * c + c0;
            atomicAdd(&eStats[j], a);
            atomicAdd(&eStats[H + j], b);
        }
    }
}

// ---------------------------------------------------------------------------
// Node update (in place, bf16 h): h = relu(bn_h(h)@V1 + aggmean@V2 + b2);
// fused h-stats; zeroes its aggsum rows. Two tiles staged before one barrier.
__global__ __launch_bounds__(256, 5) void node_kernel(unsigned short* hb,
                                                      float* __restrict__ aggsum,
                                                      const short8* __restrict__ wfrL,
                                                      const float* __restrict__ b2, int M,
                                                      const float* __restrict__ Sh,
                                                      const float* __restrict__ gh,
                                                      const float* __restrict__ bh,
                                                      float invN,
                                                      float* __restrict__ hStats)
{
    __shared__ __align__(16) unsigned short sA[64 * 128];
    __shared__ __align__(16) unsigned short sB[64 * 128];
    __shared__ float bnp[256];
    const int t = threadIdx.x, lane = t & 63, w = t >> 6, jb = 32 * w;
    const int r0 = blockIdx.x * 64;
    if (t < 128) bn_param(Sh, gh, bh, invN, t, bnp, bnp + 128);
    __syncthreads();
    stage_aff(hb, sA, r0, M, t, bnp, bnp + 128);
    stage_agg_bf16(aggsum, sB, r0, M, t);   // also zeroes consumed rows
    short8 wf[4][2];
    f32x4 acc[4][2];
    zero_acc(acc);
    load_wfrag(wfrL + 5 * 2048, w, lane, wf);   // V1
    __syncthreads();
    mfma_gemm(sA, wf, acc, lane);
    load_wfrag(wfrL + 6 * 2048, w, lane, wf);   // V2
    mfma_gemm(sB, wf, acc, lane);
    const int g = lane >> 4, c0 = lane & 15;
    float s1[2] = {0.f, 0.f}, s2[2] = {0.f, 0.f};
#pragma unroll
    for (int fr = 0; fr < 4; ++fr)
#pragma unroll
        for (int c = 0; c < 2; ++c) {
            int j = jb + 16 * c + c0;
            float bj = b2[j];
#pragma unroll
            for (int r = 0; r < 4; ++r) {
                int row = r0 + 16 * fr + 4 * g + r;
                if (row < M) {
                    float v = fmaxf(acc[fr][c][r] + bj, 0.f);
                    hb[(size_t)row * H + j] = f2bf(v);
                    s1[c] += v;
                    s2[c] += v * v;
                }
            }
        }
#pragma unroll
    for (int c = 0; c < 2; ++c) {
        float a = s1[c], b = s2[c];
        a += __shfl_xor(a, 16); a += __shfl_xor(a, 32);
        b += __shfl_xor(b, 16); b += __shfl_xor(b, 32);
        if (g == 0) {
            int j = jb + 16 * c + c0;
            atomicAdd(&hStats[j], a);
            atomicAdd(&hStats[H + j], b);
        }
    }
}

// ---------------------------------------------------------------------------
// Final readout: out = [mean(h) | mean(e)] @ reg_w + reg_b
__global__ __launch_bounds__(256) void final_kernel(const float* __restrict__ hsum,
                                                    const float* __restrict__ esum,
                                                    const float* __restrict__ reg_w,
                                                    const float* __restrict__ reg_b,
                                                    float* __restrict__ out,
                                                    float invN, float invE)
{
    __shared__ float red[256];
    int t = threadIdx.x;
    float v = (t < 128) ? hsum[t] * invN * reg_w[t]
                        : esum[t - 128] * invE * reg_w[t];
    red[t] = v;
    __syncthreads();
    for (int s = 128; s > 0; s >>= 1) {
        if (t < s) red[t] += red[t + s];
        __syncthreads();
    }
    if (t == 0) out[0] = red[0] + reg_b[0];
}

// ---------------------------------------------------------------------------
extern "C" void kernel_launch(void* const* d_in, const int* in_sizes, int n_in,
                              void* d_out, int out_size, void* d_ws, size_t ws_size,
                              hipStream_t stream)
{
    const float* x          = (const float*)d_in[0];
    const int*   edge_index = (const int*)  d_in[1];
    const float* edge_attr  = (const float*)d_in[2];
    const float* enc_node_w = (const float*)d_in[3];
    const float* enc_node_b = (const float*)d_in[4];
    const float* enc_edge_w = (const float*)d_in[5];
    const float* enc_edge_b = (const float*)d_in[6];
    const float* edge_w     = (const float*)d_in[7];
    const float* edge_b     = (const float*)d_in[8];
    const float* n1_w       = (const float*)d_in[9];
    const float* n1_b       = (const float*)d_in[10];
    const float* n2_w       = (const float*)d_in[11];
    const float* n2_b       = (const float*)d_in[12];
    const float* bn_node_g  = (const float*)d_in[13];
    const float* bn_node_b  = (const float*)d_in[14];
    const float* bn_edge_g  = (const float*)d_in[15];
    const float* bn_edge_b  = (const float*)d_in[16];
    const float* reg_w      = (const float*)d_in[17];
    const float* reg_b      = (const float*)d_in[18];

    const int N = in_sizes[0] / F_IN;
    const int E = in_sizes[1] / 2;
    const size_t NH = (size_t)N * H;
    const size_t EH = (size_t)E * H;

    float* ws     = (float*)d_ws;
    float* aggsum = ws;                 // [N,128] f32 (zeroed once; node re-zeroes)
    float* statsA = aggsum + NH;        // 512
    float* statsB = statsA + 512;       // 512
    short8* wfr   = (short8*)(statsB + 512);        // 21*2048 short8 = 672 KB
    unsigned short* hbuf = (unsigned short*)(wfr + 21 * 2048);  // [N,128] bf16
    unsigned short* ebuf = hbuf + NH;                           // [E,128] bf16 (col-sorted)
    int*   cnt_i  = (int*)(ebuf + EH);      // [N]
    int*   tmpc   = cnt_i + N;              // [N]
    int*   offs   = tmpc + N;               // [N+1]
    int*   sortedIds = offs + N + 1;        // [E]
    int*   rowS   = sortedIds + E;          // [E]
    int*   colS   = rowS + E;               // [E]

    const int* row_idx = edge_index;
    const int* col_idx = edge_index + E;
    const float invN = 1.f / (float)N;
    const float invE = 1.f / (float)E;

    // one-time: sort edges by col; bf16 weight fragments; encoders
    (void)hipMemsetAsync(cnt_i, 0, (size_t)2 * N * sizeof(int), stream);
    (void)hipMemsetAsync(aggsum, 0, NH * sizeof(float), stream);
    hist_kernel<<<(E + 255) / 256, 256, 0, stream>>>(col_idx, cnt_i, E);
    scan_kernel<<<1, 1024, 0, stream>>>(cnt_i, offs, N);
    scatter_kernel<<<(E + 255) / 256, 256, 0, stream>>>(row_idx, col_idx, offs, tmpc,
                                                        sortedIds, rowS, colS, E);
    wbf16_kernel<<<21, 256, 0, stream>>>(edge_w, n1_w, n2_w, wfr);

    enc_kernel<<<(N + 1) / 2, 256, 0, stream>>>(x, enc_node_w, enc_node_b, hbuf, N);
    enc_gather_kernel<<<(E + 1) / 2, 256, 0, stream>>>(edge_attr, sortedIds,
                                                       enc_edge_w, enc_edge_b, ebuf, E);

    const int nodeBlocks = (N + 63) / 64;
    const int edgeBlocks = (E + 63) / 64;

    for (int i = 0; i < 3; ++i) {
        float*       Scur  = (i & 1) ? statsB : statsA;
        const float* Sprev = (i == 0) ? nullptr : ((i & 1) ? statsA : statsB);
        const float* Sh = Sprev;
        const float* Se = Sprev ? Sprev + 256 : nullptr;
        const short8* wfrL = wfr + (size_t)i * 7 * 2048;
        (void)hipMemsetAsync(Scur, 0, 512 * sizeof(float), stream);
        edge_kernel<<<edgeBlocks, 256, 0, stream>>>(
            ebuf, rowS, colS, cnt_i, hbuf, wfrL,
            edge_b + i * H, n1_b + i * H,
            aggsum, E,
            Sh, bn_node_g, bn_node_b, invN,
            Se, bn_edge_g, bn_edge_b, invE,
            Scur + 256);
        node_kernel<<<nodeBlocks, 256, 0, stream>>>(
            hbuf, aggsum, wfrL, n2_b + i * H, N,
            Sh, bn_node_g, bn_node_b, invN,
            Scur);
    }
    // i=2 wrote statsA
    final_kernel<<<1, 256, 0, stream>>>(statsA, statsA + 256, reg_w, reg_b,
                                        (float*)d_out, invN, invE);
}

// Round 18
// 746.882 us; speedup vs baseline: 1.2016x; 1.0687x over previous
//
#include <hip/hip_runtime.h>

#define H 128
#define F_IN 16
#define BNEPS 1e-5f

typedef __attribute__((ext_vector_type(8))) short short8;
typedef __attribute__((ext_vector_type(4))) float f32x4;

// f32 -> bf16 round-to-nearest-even
__device__ __forceinline__ unsigned short f2bf(float f)
{
    unsigned u = __builtin_bit_cast(unsigned, f);
    u += 0x7FFFu + ((u >> 16) & 1u);
    return (unsigned short)(u >> 16);
}
__device__ __forceinline__ float bf2f(unsigned short h)
{
    return __builtin_bit_cast(float, (unsigned)h << 16);
}

// BN affine params for feature j: s[j], t[j] (identity if S==nullptr)
__device__ __forceinline__ void bn_param(const float* __restrict__ S,
                                         const float* __restrict__ g,
                                         const float* __restrict__ b,
                                         float invM, int j,
                                         float* __restrict__ sS, float* __restrict__ sT)
{
    float s = 1.f, tt = 0.f;
    if (S) {
        float mean = S[j] * invM;
        float var  = S[H + j] * invM - mean * mean;
        s  = rsqrtf(var + BNEPS) * g[j];
        tt = b[j] - mean * s;
    }
    sS[j] = s;
    sT[j] = tt;
}

// ---------------------------------------------------------------------------
// 512-thread staging: 64x128 bf16 tile with per-feature affine into swizzled
// LDS. element (row,k) -> ushort idx row*128 + (k ^ ((row&7)<<3))
__device__ __forceinline__ void stage_aff(const unsigned short* __restrict__ src,
                                          unsigned short* sA, int r0, int M, int t,
                                          const float* __restrict__ sS,
                                          const float* __restrict__ sT)
{
#pragma unroll
    for (int i = 0; i < 2; ++i) {
        int cid  = t + 512 * i;
        int row  = cid >> 4;
        int ck   = cid & 15;
        int grow = r0 + row;
        short8 v = (short8)0;
        if (grow < M) {
            v = *(const short8*)(src + (size_t)grow * H + ck * 8);
            int j0 = ck * 8;
#pragma unroll
            for (int j = 0; j < 8; ++j)
                v[j] = (short)f2bf(bf2f((unsigned short)v[j]) * sS[j0 + j] + sT[j0 + j]);
        }
        *(short8*)(sA + (row << 7) + ((ck ^ (row & 7)) << 3)) = v;
    }
}

// Gather variant: tile row i holds src[idx[p0+i]], same affine.
__device__ __forceinline__ void stage_aff_gather(const unsigned short* __restrict__ src,
                                                 const int* __restrict__ idx,
                                                 unsigned short* sA, int p0, int M, int t,
                                                 const float* __restrict__ sS,
                                                 const float* __restrict__ sT)
{
#pragma unroll
    for (int i = 0; i < 2; ++i) {
        int cid = t + 512 * i;
        int row = cid >> 4;
        int ck  = cid & 15;
        int p   = p0 + row;
        short8 v = (short8)0;
        if (p < M) {
            v = *(const short8*)(src + (size_t)idx[p] * H + ck * 8);
            int j0 = ck * 8;
#pragma unroll
            for (int j = 0; j < 8; ++j)
                v[j] = (short)f2bf(bf2f((unsigned short)v[j]) * sS[j0 + j] + sT[j0 + j]);
        }
        *(short8*)(sA + (row << 7) + ((ck ^ (row & 7)) << 3)) = v;
    }
}

// aggsum holds per-node MEANS -> convert to bf16; then zero rows for next layer
__device__ __forceinline__ void stage_agg_bf16(float* __restrict__ aggsum,
                                               unsigned short* sA, int r0, int M, int t)
{
#pragma unroll
    for (int i = 0; i < 2; ++i) {
        int cid  = t + 512 * i;
        int row  = cid >> 4;
        int ck   = cid & 15;
        int grow = r0 + row;
        short8 ph = (short8)0;
        if (grow < M) {
            float4* q = (float4*)(aggsum + (size_t)grow * H + ck * 8);
            float4 a = q[0], b = q[1];
            float xs[8] = {a.x, a.y, a.z, a.w, b.x, b.y, b.z, b.w};
#pragma unroll
            for (int j = 0; j < 8; ++j) ph[j] = (short)f2bf(xs[j]);
            q[0] = make_float4(0.f, 0.f, 0.f, 0.f);
            q[1] = make_float4(0.f, 0.f, 0.f, 0.f);
        }
        *(short8*)(sA + (row << 7) + ((ck ^ (row & 7)) << 3)) = ph;
    }
}

// ---------------------------------------------------------------------------
// One-time weight bf16 fragment precompute (21 matrices, unscaled).
__global__ __launch_bounds__(256) void wbf16_kernel(const float* __restrict__ edge_w,
                                                    const float* __restrict__ n1_w,
                                                    const float* __restrict__ n2_w,
                                                    short8* __restrict__ out)
{
    int m = blockIdx.x;
    int layer = m / 7, k = m % 7;
    const float* W = (k < 3) ? edge_w + (size_t)layer * 384 * H + (size_t)k * H * H
                   : (k < 5) ? n1_w + (size_t)layer * 256 * H + (size_t)(k - 3) * H * H
                             : n2_w + (size_t)layer * 256 * H + (size_t)(k - 5) * H * H;
    short8* oh = out + (size_t)m * 2048;
    for (int e = threadIdx.x; e < 2048; e += 256) {
        int jbB = e >> 9, s = (e >> 7) & 3, c = (e >> 6) & 1, lane = e & 63;
        int g = lane >> 4, c0 = lane & 15;
        short8 hi;
#pragma unroll
        for (int j = 0; j < 8; ++j)
            hi[j] = (short)f2bf(W[(size_t)(32 * s + 8 * g + j) * H + jbB * 32 + 16 * c + c0]);
        oh[e] = hi;
    }
}

// Wave w (0..7) owns cols [16w,16w+16): fragment idx jbB=w>>1, cB=w&1.
__device__ __forceinline__ void load_wfrag_h(const short8* __restrict__ Wp, int w,
                                             int lane, short8 wf[4])
{
    int base = ((w >> 1) * 8 + (w & 1)) * 64 + lane;   // ((jbB*4+s)*2+cB)*64+lane, s step=128
#pragma unroll
    for (int s = 0; s < 4; ++s)
        wf[s] = Wp[base + s * 128];
}

// acc[fr] += sA(64x128 bf16, swizzled) @ Wf(128x16 bf16)   (16 MFMA)
__device__ __forceinline__ void mfma_gemm_h(const unsigned short* sA, const short8 wf[4],
                                            f32x4 acc[4], int lane)
{
    const int g = lane >> 4, r = lane & 15;
#pragma unroll
    for (int s = 0; s < 4; ++s) {
        short8 a4[4];
#pragma unroll
        for (int fr = 0; fr < 4; ++fr) {
            int row = 16 * fr + r;
            int ck  = (4 * s + g) ^ (row & 7);
            a4[fr] = *(const short8*)(sA + (row << 7) + (ck << 3));
        }
#pragma unroll
        for (int fr = 0; fr < 4; ++fr)
            acc[fr] = __builtin_amdgcn_mfma_f32_16x16x32_bf16(a4[fr], wf[s], acc[fr], 0, 0, 0);
    }
}

__device__ __forceinline__ void zero_acc_h(f32x4 acc[4])
{
#pragma unroll
    for (int fr = 0; fr < 4; ++fr) {
        acc[fr][0] = 0.f; acc[fr][1] = 0.f; acc[fr][2] = 0.f; acc[fr][3] = 0.f;
    }
}

// ---------------------------------------------------------------------------
// One-time sort machinery (edge_index is layer-invariant)
__global__ __launch_bounds__(256) void hist_kernel(const int* __restrict__ col,
                                                   int* __restrict__ cnt, int E)
{
    int e = blockIdx.x * 256 + threadIdx.x;
    if (e < E) atomicAdd(&cnt[col[e]], 1);
}

__global__ __launch_bounds__(1024) void scan_kernel(const int* __restrict__ cnt,
                                                    int* __restrict__ offs, int Nn)
{
    __shared__ int ls[1024];
    int t = threadIdx.x;
    int per = (Nn + 1023) / 1024;
    int base = t * per;
    int s = 0;
    for (int k = 0; k < per; ++k) {
        int i = base + k;
        if (i < Nn) s += cnt[i];
    }
    ls[t] = s;
    __syncthreads();
    for (int d = 1; d < 1024; d <<= 1) {
        int u = (t >= d) ? ls[t - d] : 0;
        __syncthreads();
        ls[t] += u;
        __syncthreads();
    }
    int run = ls[t] - s;
    for (int k = 0; k < per; ++k) {
        int i = base + k;
        if (i < Nn) {
            offs[i] = run;
            run += cnt[i];
        }
    }
}

__global__ __launch_bounds__(256) void scatter_kernel(const int* __restrict__ row,
                                                      const int* __restrict__ col,
                                                      const int* __restrict__ offs,
                                                      int* __restrict__ tmpc,
                                                      int* __restrict__ sortedIds,
                                                      int* __restrict__ rowS,
                                                      int* __restrict__ colS, int E)
{
    int e = blockIdx.x * 256 + threadIdx.x;
    if (e < E) {
        int c = col[e];
        int p = offs[c] + atomicAdd(&tmpc[c], 1);
        sortedIds[p] = e;
        rowS[p] = row[e];
        colS[p] = c;
    }
}

// ---------------------------------------------------------------------------
// Encoder: out(bf16) = relu(X[M,16] @ W[16,128] + b)
__global__ __launch_bounds__(256) void enc_kernel(const float* __restrict__ X,
                                                  const float* __restrict__ W,
                                                  const float* __restrict__ bias,
                                                  unsigned short* __restrict__ out, int M)
{
    __shared__ float sW[F_IN * H];
    __shared__ float sb[H];
    int t = threadIdx.x;
    reinterpret_cast<float4*>(sW)[t]       = reinterpret_cast<const float4*>(W)[t];
    reinterpret_cast<float4*>(sW)[t + 256] = reinterpret_cast<const float4*>(W)[t + 256];
    if (t < H) sb[t] = bias[t];
    __syncthreads();
    int row = blockIdx.x * 2 + (t >> 7);
    if (row >= M) return;
    int j = t & 127;
    float acc = sb[j];
#pragma unroll
    for (int k = 0; k < F_IN; ++k)
        acc += X[(size_t)row * F_IN + k] * sW[k * H + j];
    out[(size_t)row * H + j] = f2bf(fmaxf(acc, 0.f));
}

// Gather-encoder: out[p](bf16) = relu(X[sortedIds[p],16] @ W + b)
__global__ __launch_bounds__(256) void enc_gather_kernel(const float* __restrict__ X,
                                                         const int* __restrict__ sortedIds,
                                                         const float* __restrict__ W,
                                                         const float* __restrict__ bias,
                                                         unsigned short* __restrict__ out,
                                                         int M)
{
    __shared__ float sW[F_IN * H];
    __shared__ float sb[H];
    int t = threadIdx.x;
    reinterpret_cast<float4*>(sW)[t]       = reinterpret_cast<const float4*>(W)[t];
    reinterpret_cast<float4*>(sW)[t + 256] = reinterpret_cast<const float4*>(W)[t + 256];
    if (t < H) sb[t] = bias[t];
    __syncthreads();
    int p = blockIdx.x * 2 + (t >> 7);
    if (p >= M) return;
    int src = sortedIds[p];
    int j = t & 127;
    float acc = sb[j];
#pragma unroll
    for (int k = 0; k < F_IN; ++k)
        acc += X[(size_t)src * F_IN + k] * sW[k * H + j];
    out[(size_t)p * H + j] = f2bf(fmaxf(acc, 0.f));
}

// ---------------------------------------------------------------------------
// Fused edge kernel, 512 threads (8 waves x 16-col strips):
//   e'[p] = relu(bn_e(e[p])@W3 + bn_h(h[rowS])@W1 + bn_h(h[colS])@W2 + be)
//   m     = relu(e'@U2 + bn_h(h[rowS])@U1 + b1)
//   aggsum[col] += segment-MEAN partials ; fused e'-stats
__global__ __launch_bounds__(512, 3) void edge_kernel(unsigned short* eb,
                                                      const int* __restrict__ rowS,
                                                      const int* __restrict__ colS,
                                                      const int* __restrict__ cnt,
                                                      const unsigned short* __restrict__ hb,
                                                      const short8* __restrict__ wfrL,
                                                      const float* __restrict__ be,
                                                      const float* __restrict__ b1,
                                                      float* __restrict__ aggsum, int E,
                                                      const float* __restrict__ Sh,
                                                      const float* __restrict__ gh,
                                                      const float* __restrict__ bh,
                                                      float invN,
                                                      const float* __restrict__ Se,
                                                      const float* __restrict__ ge,
                                                      const float* __restrict__ beB,
                                                      float invE,
                                                      float* __restrict__ eStats)
{
    __shared__ __align__(16) unsigned char smem[64 * 128 * 6 + 256 + 256 + 2048];
    unsigned short* sE  = (unsigned short*)smem;          // 16 KB  e (bf16)
    unsigned short* sHt = sE + 64 * 128;                  // 16 KB  h[rowS] (bf16)
    unsigned short* sHc = sHt + 64 * 128;                 // 16 KB  h[colS] (bf16)
    float*          mbuf = (float*)smem;                  // 32 KB overlay sE+sHt
    int*            scol = (int*)(smem + 64 * 128 * 6);          // 256 B
    float*          sinv = (float*)(smem + 64 * 128 * 6 + 256);  // 256 B
    float*          bnp  = (float*)(smem + 64 * 128 * 6 + 512);  // 2 KB

    const int t = threadIdx.x, lane = t & 63, w = t >> 6;
    const int e0 = blockIdx.x * 64;
    const int g = lane >> 4, c0 = lane & 15;
    const int j = 16 * w + c0;        // this lane's output column

    if (t < 64) {
        int cc = colS[(e0 + t < E) ? (e0 + t) : (E - 1)];
        scol[t] = cc;
        int c = cnt[cc];
        sinv[t] = 1.f / (float)(c > 1 ? c : 1);
    }
    if (t >= 64 && t < 192)      bn_param(Sh, gh, bh, invN, t - 64, bnp, bnp + 128);
    else if (t >= 192 && t < 320) bn_param(Se, ge, beB, invE, t - 192, bnp + 256, bnp + 384);
    __syncthreads();   // bnp + scol ready

    stage_aff(eb, sE, e0, E, t, bnp + 256, bnp + 384);
    stage_aff_gather(hb, rowS, sHt, e0, E, t, bnp, bnp + 128);
    {
        int Mt = E - e0; if (Mt > 64) Mt = 64;
        stage_aff_gather(hb, scol, sHc, 0, Mt, t, bnp, bnp + 128);
    }

    short8 wf[4];
    f32x4 acc[4];
    zero_acc_h(acc);
    load_wfrag_h(wfrL + 2 * 2048, w, lane, wf);   // W3
    __syncthreads();
    mfma_gemm_h(sE, wf, acc, lane);
    load_wfrag_h(wfrL + 0 * 2048, w, lane, wf);   // W1
    mfma_gemm_h(sHt, wf, acc, lane);
    load_wfrag_h(wfrL + 1 * 2048, w, lane, wf);   // W2 (B-term)
    mfma_gemm_h(sHc, wf, acc, lane);
    __syncthreads();   // all reads of sE done -> safe to overwrite with e'

    // epilogue 1: e' = relu(acc + be) -> bf16 global + back to sE
    float s1 = 0.f, s2 = 0.f;
    {
        float bej = be[j];
#pragma unroll
        for (int fr = 0; fr < 4; ++fr)
#pragma unroll
            for (int r = 0; r < 4; ++r) {
                int Rl = 16 * fr + 4 * g + r;
                int p  = e0 + Rl;
                float v = acc[fr][r] + bej;
                v = fmaxf(v, 0.f);
                unsigned short vb = f2bf(v);
                if (p < E) {
                    eb[(size_t)p * H + j] = vb;
                    s1 += v;
                    s2 += v * v;
                }
                sE[(Rl << 7) + (j ^ ((Rl & 7) << 3))] = vb;
            }
    }
    __syncthreads();

    // GEMM2: m = e'@U2 + bn_h(h[rowS])@U1
    zero_acc_h(acc);
    load_wfrag_h(wfrL + 4 * 2048, w, lane, wf);   // U2
    mfma_gemm_h(sE, wf, acc, lane);
    load_wfrag_h(wfrL + 3 * 2048, w, lane, wf);   // U1
    mfma_gemm_h(sHt, wf, acc, lane);
    __syncthreads();   // all GEMM2 LDS reads done -> mbuf overlay safe

    // epilogue 2: m -> mbuf (swizzled)
    {
        float b1j = b1[j];
#pragma unroll
        for (int fr = 0; fr < 4; ++fr)
#pragma unroll
            for (int r = 0; r < 4; ++r) {
                int Rl = 16 * fr + 4 * g + r;
                float v = fmaxf(acc[fr][r] + b1j, 0.f);
                mbuf[(Rl << 7) + (j ^ (((Rl >> 2) & 3) << 3))] = v;
            }
    }
    __syncthreads();

    // segmented reduction, 4-way parallel over row quarters (512 threads):
    // thread (jc = t&127, q = t>>7) walks rows [16q,16q+16), emits mean partials
    {
        int jc = t & 127, q = t >> 7;
        int rbeg = q * 16, rend = rbeg + 16;
        int rlim = E - e0;
        float run = 0.f;
        int cur = scol[rbeg];
        for (int row = rbeg; row < rend; ++row) {
            int cc = scol[row];
            float v = mbuf[(row << 7) + (jc ^ (((row >> 2) & 3) << 3))];
            if (cc != cur) {
                if (run != 0.f)
                    atomicAdd(&aggsum[(size_t)cur * H + jc], run * sinv[row - 1]);
                run = 0.f;
                cur = cc;
            }
            if (row < rlim) run += v;
        }
        if (run != 0.f)
            atomicAdd(&aggsum[(size_t)cur * H + jc], run * sinv[rend - 1]);
    }

    // fused e'-stats: reduce across the 4 row-groups (lanes differing in g)
    {
        float a = s1, b = s2;
        a += __shfl_xor(a, 16); a += __shfl_xor(a, 32);
        b += __shfl_xor(b, 16); b += __shfl_xor(b, 32);
        if (g == 0) {
            atomicAdd(&eStats[j], a);
            atomicAdd(&eStats[H + j], b);
        }
    }
}

// ---------------------------------------------------------------------------
// Node update, 512 threads: h = relu(bn_h(h)@V1 + aggmean@V2 + b2);
// fused h-stats; zeroes its aggsum rows.
__global__ __launch_bounds__(512, 4) void node_kernel(unsigned short* hb,
                                                      float* __restrict__ aggsum,
                                                      const short8* __restrict__ wfrL,
                                                      const float* __restrict__ b2, int M,
                                                      const float* __restrict__ Sh,
                                                      const float* __restrict__ gh,
                                                      const float* __restrict__ bh,
                                                      float invN,
                                                      float* __restrict__ hStats)
{
    __shared__ __align__(16) unsigned short sA[64 * 128];
    __shared__ __align__(16) unsigned short sB[64 * 128];
    __shared__ float bnp[256];
    const int t = threadIdx.x, lane = t & 63, w = t >> 6;
    const int r0 = blockIdx.x * 64;
    const int g = lane >> 4, c0 = lane & 15;
    const int j = 16 * w + c0;
    if (t < 128) bn_param(Sh, gh, bh, invN, t, bnp, bnp + 128);
    __syncthreads();
    stage_aff(hb, sA, r0, M, t, bnp, bnp + 128);
    stage_agg_bf16(aggsum, sB, r0, M, t);   // also zeroes consumed rows
    short8 wf[4];
    f32x4 acc[4];
    zero_acc_h(acc);
    load_wfrag_h(wfrL + 5 * 2048, w, lane, wf);   // V1
    __syncthreads();
    mfma_gemm_h(sA, wf, acc, lane);
    load_wfrag_h(wfrL + 6 * 2048, w, lane, wf);   // V2
    mfma_gemm_h(sB, wf, acc, lane);
    float s1 = 0.f, s2 = 0.f;
    {
        float bj = b2[j];
#pragma unroll
        for (int fr = 0; fr < 4; ++fr)
#pragma unroll
            for (int r = 0; r < 4; ++r) {
                int row = r0 + 16 * fr + 4 * g + r;
                if (row < M) {
                    float v = fmaxf(acc[fr][r] + bj, 0.f);
                    hb[(size_t)row * H + j] = f2bf(v);
                    s1 += v;
                    s2 += v * v;
                }
            }
    }
    {
        float a = s1, b = s2;
        a += __shfl_xor(a, 16); a += __shfl_xor(a, 32);
        b += __shfl_xor(b, 16); b += __shfl_xor(b, 32);
        if (g == 0) {
            atomicAdd(&hStats[j], a);
            atomicAdd(&hStats[H + j], b);
        }
    }
}

// ---------------------------------------------------------------------------
// Final readout: out = [mean(h) | mean(e)] @ reg_w + reg_b
__global__ __launch_bounds__(256) void final_kernel(const float* __restrict__ hsum,
                                                    const float* __restrict__ esum,
                                                    const float* __restrict__ reg_w,
                                                    const float* __restrict__ reg_b,
                                                    float* __restrict__ out,
                                                    float invN, float invE)
{
    __shared__ float red[256];
    int t = threadIdx.x;
    float v = (t < 128) ? hsum[t] * invN * reg_w[t]
                        : esum[t - 128] * invE * reg_w[t];
    red[t] = v;
    __syncthreads();
    for (int s = 128; s > 0; s >>= 1) {
        if (t < s) red[t] += red[t + s];
        __syncthreads();
    }
    if (t == 0) out[0] = red[0] + reg_b[0];
}

// ---------------------------------------------------------------------------
extern "C" void kernel_launch(void* const* d_in, const int* in_sizes, int n_in,
                              void* d_out, int out_size, void* d_ws, size_t ws_size,
                              hipStream_t stream)
{
    const float* x          = (const float*)d_in[0];
    const int*   edge_index = (const int*)  d_in[1];
    const float* edge_attr  = (const float*)d_in[2];
    const float* enc_node_w = (const float*)d_in[3];
    const float* enc_node_b = (const float*)d_in[4];
    const float* enc_edge_w = (const float*)d_in[5];
    const float* enc_edge_b = (const float*)d_in[6];
    const float* edge_w     = (const float*)d_in[7];
    const float* edge_b     = (const float*)d_in[8];
    const float* n1_w       = (const float*)d_in[9];
    const float* n1_b       = (const float*)d_in[10];
    const float* n2_w       = (const float*)d_in[11];
    const float* n2_b       = (const float*)d_in[12];
    const float* bn_node_g  = (const float*)d_in[13];
    const float* bn_node_b  = (const float*)d_in[14];
    const float* bn_edge_g  = (const float*)d_in[15];
    const float* bn_edge_b  = (const float*)d_in[16];
    const float* reg_w      = (const float*)d_in[17];
    const float* reg_b      = (const float*)d_in[18];

    const int N = in_sizes[0] / F_IN;
    const int E = in_sizes[1] / 2;
    const size_t NH = (size_t)N * H;
    const size_t EH = (size_t)E * H;

    float* ws     = (float*)d_ws;
    float* aggsum = ws;                 // [N,128] f32 (zeroed once; node re-zeroes)
    float* statsA = aggsum + NH;        // 512
    float* statsB = statsA + 512;       // 512
    short8* wfr   = (short8*)(statsB + 512);        // 21*2048 short8 = 672 KB
    unsigned short* hbuf = (unsigned short*)(wfr + 21 * 2048);  // [N,128] bf16
    unsigned short* ebuf = hbuf + NH;                           // [E,128] bf16 (col-sorted)
    int*   cnt_i  = (int*)(ebuf + EH);      // [N]
    int*   tmpc   = cnt_i + N;              // [N]
    int*   offs   = tmpc + N;               // [N+1]
    int*   sortedIds = offs + N + 1;        // [E]
    int*   rowS   = sortedIds + E;          // [E]
    int*   colS   = rowS + E;               // [E]

    const int* row_idx = edge_index;
    const int* col_idx = edge_index + E;
    const float invN = 1.f / (float)N;
    const float invE = 1.f / (float)E;

    // one-time: sort edges by col; bf16 weight fragments; encoders
    (void)hipMemsetAsync(cnt_i, 0, (size_t)2 * N * sizeof(int), stream);
    (void)hipMemsetAsync(aggsum, 0, NH * sizeof(float), stream);
    hist_kernel<<<(E + 255) / 256, 256, 0, stream>>>(col_idx, cnt_i, E);
    scan_kernel<<<1, 1024, 0, stream>>>(cnt_i, offs, N);
    scatter_kernel<<<(E + 255) / 256, 256, 0, stream>>>(row_idx, col_idx, offs, tmpc,
                                                        sortedIds, rowS, colS, E);
    wbf16_kernel<<<21, 256, 0, stream>>>(edge_w, n1_w, n2_w, wfr);

    enc_kernel<<<(N + 1) / 2, 256, 0, stream>>>(x, enc_node_w, enc_node_b, hbuf, N);
    enc_gather_kernel<<<(E + 1) / 2, 256, 0, stream>>>(edge_attr, sortedIds,
                                                       enc_edge_w, enc_edge_b, ebuf, E);

    const int nodeBlocks = (N + 63) / 64;
    const int edgeBlocks = (E + 63) / 64;

    for (int i = 0; i < 3; ++i) {
        float*       Scur  = (i & 1) ? statsB : statsA;
        const float* Sprev = (i == 0) ? nullptr : ((i & 1) ? statsA : statsB);
        const float* Sh = Sprev;
        const float* Se = Sprev ? Sprev + 256 : nullptr;
        const short8* wfrL = wfr + (size_t)i * 7 * 2048;
        (void)hipMemsetAsync(Scur, 0, 512 * sizeof(float), stream);
        edge_kernel<<<edgeBlocks, 512, 0, stream>>>(
            ebuf, rowS, colS, cnt_i, hbuf, wfrL,
            edge_b + i * H, n1_b + i * H,
            aggsum, E,
            Sh, bn_node_g, bn_node_b, invN,
            Se, bn_edge_g, bn_edge_b, invE,
            Scur + 256);
        node_kernel<<<nodeBlocks, 512, 0, stream>>>(
            hbuf, aggsum, wfrL, n2_b + i * H, N,
            Sh, bn_node_g, bn_node_b, invN,
            Scur);
    }
    // i=2 wrote statsA
    final_kernel<<<1, 256, 0, stream>>>(statsA, statsA + 256, reg_w, reg_b,
                                        (float*)d_out, invN, invE);
}

// Round 19
// 743.663 us; speedup vs baseline: 1.2068x; 1.0043x over previous
//
#include <hip/hip_runtime.h>

#define H 128
#define F_IN 16
#define BNEPS 1e-5f

typedef __attribute__((ext_vector_type(8))) short short8;
typedef __attribute__((ext_vector_type(4))) float f32x4;

// f32 -> bf16 round-to-nearest-even
__device__ __forceinline__ unsigned short f2bf(float f)
{
    unsigned u = __builtin_bit_cast(unsigned, f);
    u += 0x7FFFu + ((u >> 16) & 1u);
    return (unsigned short)(u >> 16);
}
__device__ __forceinline__ float bf2f(unsigned short h)
{
    return __builtin_bit_cast(float, (unsigned)h << 16);
}

// BN affine params for feature j: s[j], t[j] (identity if S==nullptr)
__device__ __forceinline__ void bn_param(const float* __restrict__ S,
                                         const float* __restrict__ g,
                                         const float* __restrict__ b,
                                         float invM, int j,
                                         float* __restrict__ sS, float* __restrict__ sT)
{
    float s = 1.f, tt = 0.f;
    if (S) {
        float mean = S[j] * invM;
        float var  = S[H + j] * invM - mean * mean;
        s  = rsqrtf(var + BNEPS) * g[j];
        tt = b[j] - mean * s;
    }
    sS[j] = s;
    sT[j] = tt;
}

// ---------------------------------------------------------------------------
// 512-thread staging: 64x128 bf16 tile with per-feature affine into swizzled
// LDS. element (row,k) -> ushort idx row*128 + (k ^ ((row&7)<<3))
__device__ __forceinline__ void stage_aff(const unsigned short* __restrict__ src,
                                          unsigned short* sA, int r0, int M, int t,
                                          const float* __restrict__ sS,
                                          const float* __restrict__ sT)
{
#pragma unroll
    for (int i = 0; i < 2; ++i) {
        int cid  = t + 512 * i;
        int row  = cid >> 4;
        int ck   = cid & 15;
        int grow = r0 + row;
        short8 v = (short8)0;
        if (grow < M) {
            v = *(const short8*)(src + (size_t)grow * H + ck * 8);
            int j0 = ck * 8;
#pragma unroll
            for (int j = 0; j < 8; ++j)
                v[j] = (short)f2bf(bf2f((unsigned short)v[j]) * sS[j0 + j] + sT[j0 + j]);
        }
        *(short8*)(sA + (row << 7) + ((ck ^ (row & 7)) << 3)) = v;
    }
}

// Gather variant: tile row i holds src[idx[p0+i]], same affine.
__device__ __forceinline__ void stage_aff_gather(const unsigned short* __restrict__ src,
                                                 const int* __restrict__ idx,
                                                 unsigned short* sA, int p0, int M, int t,
                                                 const float* __restrict__ sS,
                                                 const float* __restrict__ sT)
{
#pragma unroll
    for (int i = 0; i < 2; ++i) {
        int cid = t + 512 * i;
        int row = cid >> 4;
        int ck  = cid & 15;
        int p   = p0 + row;
        short8 v = (short8)0;
        if (p < M) {
            v = *(const short8*)(src + (size_t)idx[p] * H + ck * 8);
            int j0 = ck * 8;
#pragma unroll
            for (int j = 0; j < 8; ++j)
                v[j] = (short)f2bf(bf2f((unsigned short)v[j]) * sS[j0 + j] + sT[j0 + j]);
        }
        *(short8*)(sA + (row << 7) + ((ck ^ (row & 7)) << 3)) = v;
    }
}

// aggsum holds per-node MEANS -> convert to bf16; then zero rows for next layer
__device__ __forceinline__ void stage_agg_bf16(float* __restrict__ aggsum,
                                               unsigned short* sA, int r0, int M, int t)
{
#pragma unroll
    for (int i = 0; i < 2; ++i) {
        int cid  = t + 512 * i;
        int row  = cid >> 4;
        int ck   = cid & 15;
        int grow = r0 + row;
        short8 ph = (short8)0;
        if (grow < M) {
            float4* q = (float4*)(aggsum + (size_t)grow * H + ck * 8);
            float4 a = q[0], b = q[1];
            float xs[8] = {a.x, a.y, a.z, a.w, b.x, b.y, b.z, b.w};
#pragma unroll
            for (int j = 0; j < 8; ++j) ph[j] = (short)f2bf(xs[j]);
            q[0] = make_float4(0.f, 0.f, 0.f, 0.f);
            q[1] = make_float4(0.f, 0.f, 0.f, 0.f);
        }
        *(short8*)(sA + (row << 7) + ((ck ^ (row & 7)) << 3)) = ph;
    }
}

// ---------------------------------------------------------------------------
// One-time weight bf16 fragment precompute (21 matrices, unscaled).
__global__ __launch_bounds__(256) void wbf16_kernel(const float* __restrict__ edge_w,
                                                    const float* __restrict__ n1_w,
                                                    const float* __restrict__ n2_w,
                                                    short8* __restrict__ out)
{
    int m = blockIdx.x;
    int layer = m / 7, k = m % 7;
    const float* W = (k < 3) ? edge_w + (size_t)layer * 384 * H + (size_t)k * H * H
                   : (k < 5) ? n1_w + (size_t)layer * 256 * H + (size_t)(k - 3) * H * H
                             : n2_w + (size_t)layer * 256 * H + (size_t)(k - 5) * H * H;
    short8* oh = out + (size_t)m * 2048;
    for (int e = threadIdx.x; e < 2048; e += 256) {
        int jbB = e >> 9, s = (e >> 7) & 3, c = (e >> 6) & 1, lane = e & 63;
        int g = lane >> 4, c0 = lane & 15;
        short8 hi;
#pragma unroll
        for (int j = 0; j < 8; ++j)
            hi[j] = (short)f2bf(W[(size_t)(32 * s + 8 * g + j) * H + jbB * 32 + 16 * c + c0]);
        oh[e] = hi;
    }
}

// Wave w (0..7) owns cols [16w,16w+16): fragment idx jbB=w>>1, cB=w&1.
__device__ __forceinline__ void load_wfrag_h(const short8* __restrict__ Wp, int w,
                                             int lane, short8 wf[4])
{
    int base = ((w >> 1) * 8 + (w & 1)) * 64 + lane;
#pragma unroll
    for (int s = 0; s < 4; ++s)
        wf[s] = Wp[base + s * 128];
}

// acc[fr] += sA(64x128 bf16, swizzled) @ Wf(128x16 bf16)   (16 MFMA)
__device__ __forceinline__ void mfma_gemm_h(const unsigned short* sA, const short8 wf[4],
                                            f32x4 acc[4], int lane)
{
    const int g = lane >> 4, r = lane & 15;
#pragma unroll
    for (int s = 0; s < 4; ++s) {
        short8 a4[4];
#pragma unroll
        for (int fr = 0; fr < 4; ++fr) {
            int row = 16 * fr + r;
            int ck  = (4 * s + g) ^ (row & 7);
            a4[fr] = *(const short8*)(sA + (row << 7) + (ck << 3));
        }
#pragma unroll
        for (int fr = 0; fr < 4; ++fr)
            acc[fr] = __builtin_amdgcn_mfma_f32_16x16x32_bf16(a4[fr], wf[s], acc[fr], 0, 0, 0);
    }
}

__device__ __forceinline__ void zero_acc_h(f32x4 acc[4])
{
#pragma unroll
    for (int fr = 0; fr < 4; ++fr) {
        acc[fr][0] = 0.f; acc[fr][1] = 0.f; acc[fr][2] = 0.f; acc[fr][3] = 0.f;
    }
}

// ---------------------------------------------------------------------------
// One-time sort machinery (edge_index is layer-invariant)
__global__ __launch_bounds__(256) void hist_kernel(const int* __restrict__ col,
                                                   int* __restrict__ cnt, int E)
{
    int e = blockIdx.x * 256 + threadIdx.x;
    if (e < E) atomicAdd(&cnt[col[e]], 1);
}

__global__ __launch_bounds__(1024) void scan_kernel(const int* __restrict__ cnt,
                                                    int* __restrict__ offs, int Nn)
{
    __shared__ int ls[1024];
    int t = threadIdx.x;
    int per = (Nn + 1023) / 1024;
    int base = t * per;
    int s = 0;
    for (int k = 0; k < per; ++k) {
        int i = base + k;
        if (i < Nn) s += cnt[i];
    }
    ls[t] = s;
    __syncthreads();
    for (int d = 1; d < 1024; d <<= 1) {
        int u = (t >= d) ? ls[t - d] : 0;
        __syncthreads();
        ls[t] += u;
        __syncthreads();
    }
    int run = ls[t] - s;
    for (int k = 0; k < per; ++k) {
        int i = base + k;
        if (i < Nn) {
            offs[i] = run;
            run += cnt[i];
        }
    }
}

__global__ __launch_bounds__(256) void scatter_kernel(const int* __restrict__ row,
                                                      const int* __restrict__ col,
                                                      const int* __restrict__ offs,
                                                      int* __restrict__ tmpc,
                                                      int* __restrict__ sortedIds,
                                                      int* __restrict__ rowS,
                                                      int* __restrict__ colS, int E)
{
    int e = blockIdx.x * 256 + threadIdx.x;
    if (e < E) {
        int c = col[e];
        int p = offs[c] + atomicAdd(&tmpc[c], 1);
        sortedIds[p] = e;
        rowS[p] = row[e];
        colS[p] = c;
    }
}

// ---------------------------------------------------------------------------
// Encoder: out(bf16) = relu(X[M,16] @ W[16,128] + b)
__global__ __launch_bounds__(256) void enc_kernel(const float* __restrict__ X,
                                                  const float* __restrict__ W,
                                                  const float* __restrict__ bias,
                                                  unsigned short* __restrict__ out, int M)
{
    __shared__ float sW[F_IN * H];
    __shared__ float sb[H];
    int t = threadIdx.x;
    reinterpret_cast<float4*>(sW)[t]       = reinterpret_cast<const float4*>(W)[t];
    reinterpret_cast<float4*>(sW)[t + 256] = reinterpret_cast<const float4*>(W)[t + 256];
    if (t < H) sb[t] = bias[t];
    __syncthreads();
    int row = blockIdx.x * 2 + (t >> 7);
    if (row >= M) return;
    int j = t & 127;
    float acc = sb[j];
#pragma unroll
    for (int k = 0; k < F_IN; ++k)
        acc += X[(size_t)row * F_IN + k] * sW[k * H + j];
    out[(size_t)row * H + j] = f2bf(fmaxf(acc, 0.f));
}

// Gather-encoder: out[p](bf16) = relu(X[sortedIds[p],16] @ W + b)
__global__ __launch_bounds__(256) void enc_gather_kernel(const float* __restrict__ X,
                                                         const int* __restrict__ sortedIds,
                                                         const float* __restrict__ W,
                                                         const float* __restrict__ bias,
                                                         unsigned short* __restrict__ out,
                                                         int M)
{
    __shared__ float sW[F_IN * H];
    __shared__ float sb[H];
    int t = threadIdx.x;
    reinterpret_cast<float4*>(sW)[t]       = reinterpret_cast<const float4*>(W)[t];
    reinterpret_cast<float4*>(sW)[t + 256] = reinterpret_cast<const float4*>(W)[t + 256];
    if (t < H) sb[t] = bias[t];
    __syncthreads();
    int p = blockIdx.x * 2 + (t >> 7);
    if (p >= M) return;
    int src = sortedIds[p];
    int j = t & 127;
    float acc = sb[j];
#pragma unroll
    for (int k = 0; k < F_IN; ++k)
        acc += X[(size_t)src * F_IN + k] * sW[k * H + j];
    out[(size_t)p * H + j] = f2bf(fmaxf(acc, 0.f));
}

// ---------------------------------------------------------------------------
// Fused edge kernel, 512 threads (8 waves x 16-col strips):
//   e'[p] = relu(bn_e(e[p])@W3 + bn_h(h[rowS])@W1 + bn_h(h[colS])@W2 + be)
//   m     = relu(e'@U2 + bn_h(h[rowS])@U1 + b1)
//   aggsum[col] += segment-MEAN partials ; fused e'-stats
//   e' written to global via coalesced LDS stage-out.
__global__ __launch_bounds__(512, 3) void edge_kernel(unsigned short* eb,
                                                      const int* __restrict__ rowS,
                                                      const int* __restrict__ colS,
                                                      const int* __restrict__ cnt,
                                                      const unsigned short* __restrict__ hb,
                                                      const short8* __restrict__ wfrL,
                                                      const float* __restrict__ be,
                                                      const float* __restrict__ b1,
                                                      float* __restrict__ aggsum, int E,
                                                      const float* __restrict__ Sh,
                                                      const float* __restrict__ gh,
                                                      const float* __restrict__ bh,
                                                      float invN,
                                                      const float* __restrict__ Se,
                                                      const float* __restrict__ ge,
                                                      const float* __restrict__ beB,
                                                      float invE,
                                                      float* __restrict__ eStats)
{
    __shared__ __align__(16) unsigned char smem[64 * 128 * 6 + 256 + 256 + 2048];
    unsigned short* sE  = (unsigned short*)smem;          // 16 KB  e (bf16)
    unsigned short* sHt = sE + 64 * 128;                  // 16 KB  h[rowS] (bf16)
    unsigned short* sHc = sHt + 64 * 128;                 // 16 KB  h[colS] (bf16)
    float*          mbuf = (float*)smem;                  // 32 KB overlay sE+sHt
    int*            scol = (int*)(smem + 64 * 128 * 6);          // 256 B
    float*          sinv = (float*)(smem + 64 * 128 * 6 + 256);  // 256 B
    float*          bnp  = (float*)(smem + 64 * 128 * 6 + 512);  // 2 KB

    const int t = threadIdx.x, lane = t & 63, w = t >> 6;
    const int e0 = blockIdx.x * 64;
    const int g = lane >> 4, c0 = lane & 15;
    const int j = 16 * w + c0;        // this lane's output column

    if (t < 64) {
        int cc = colS[(e0 + t < E) ? (e0 + t) : (E - 1)];
        scol[t] = cc;
        int c = cnt[cc];
        sinv[t] = 1.f / (float)(c > 1 ? c : 1);
    }
    if (t >= 64 && t < 192)      bn_param(Sh, gh, bh, invN, t - 64, bnp, bnp + 128);
    else if (t >= 192 && t < 320) bn_param(Se, ge, beB, invE, t - 192, bnp + 256, bnp + 384);
    __syncthreads();   // bnp + scol ready

    stage_aff(eb, sE, e0, E, t, bnp + 256, bnp + 384);
    stage_aff_gather(hb, rowS, sHt, e0, E, t, bnp, bnp + 128);
    {
        int Mt = E - e0; if (Mt > 64) Mt = 64;
        stage_aff_gather(hb, scol, sHc, 0, Mt, t, bnp, bnp + 128);
    }

    short8 wf[4];
    f32x4 acc[4];
    zero_acc_h(acc);
    load_wfrag_h(wfrL + 2 * 2048, w, lane, wf);   // W3
    __syncthreads();
    mfma_gemm_h(sE, wf, acc, lane);
    load_wfrag_h(wfrL + 0 * 2048, w, lane, wf);   // W1
    mfma_gemm_h(sHt, wf, acc, lane);
    load_wfrag_h(wfrL + 1 * 2048, w, lane, wf);   // W2 (B-term)
    mfma_gemm_h(sHc, wf, acc, lane);
    __syncthreads();   // all reads of sE done -> safe to overwrite with e'

    // epilogue 1: e' = relu(acc + be) -> sE (swizzled) + stats in registers
    float s1 = 0.f, s2 = 0.f;
    {
        float bej = be[j];
#pragma unroll
        for (int fr = 0; fr < 4; ++fr)
#pragma unroll
            for (int r = 0; r < 4; ++r) {
                int Rl = 16 * fr + 4 * g + r;
                int p  = e0 + Rl;
                float v = acc[fr][r] + bej;
                v = fmaxf(v, 0.f);
                unsigned short vb = f2bf(v);
                if (p < E) {
                    s1 += v;
                    s2 += v * v;
                }
                sE[(Rl << 7) + (j ^ ((Rl & 7) << 3))] = vb;
            }
    }
    __syncthreads();   // sE complete

    // coalesced e' stage-out: 2 x 16B stores per thread (reads sE, unswizzled)
#pragma unroll
    for (int i = 0; i < 2; ++i) {
        int cid = t + 512 * i;
        int row = cid >> 4;
        int ck  = cid & 15;
        int p   = e0 + row;
        if (p < E) {
            short8 v = *(const short8*)(sE + (row << 7) + ((ck ^ (row & 7)) << 3));
            *(short8*)(eb + (size_t)p * H + ck * 8) = v;
        }
    }

    // GEMM2: m = e'@U2 + bn_h(h[rowS])@U1
    zero_acc_h(acc);
    load_wfrag_h(wfrL + 4 * 2048, w, lane, wf);   // U2
    mfma_gemm_h(sE, wf, acc, lane);
    load_wfrag_h(wfrL + 3 * 2048, w, lane, wf);   // U1
    mfma_gemm_h(sHt, wf, acc, lane);
    __syncthreads();   // all GEMM2 LDS reads done -> mbuf overlay safe

    // epilogue 2: m -> mbuf (swizzled)
    {
        float b1j = b1[j];
#pragma unroll
        for (int fr = 0; fr < 4; ++fr)
#pragma unroll
            for (int r = 0; r < 4; ++r) {
                int Rl = 16 * fr + 4 * g + r;
                float v = fmaxf(acc[fr][r] + b1j, 0.f);
                mbuf[(Rl << 7) + (j ^ (((Rl >> 2) & 3) << 3))] = v;
            }
    }
    __syncthreads();

    // segmented reduction, 4-way parallel over row quarters (512 threads)
    {
        int jc = t & 127, q = t >> 7;
        int rbeg = q * 16, rend = rbeg + 16;
        int rlim = E - e0;
        float run = 0.f;
        int cur = scol[rbeg];
        for (int row = rbeg; row < rend; ++row) {
            int cc = scol[row];
            float v = mbuf[(row << 7) + (jc ^ (((row >> 2) & 3) << 3))];
            if (cc != cur) {
                if (run != 0.f)
                    atomicAdd(&aggsum[(size_t)cur * H + jc], run * sinv[row - 1]);
                run = 0.f;
                cur = cc;
            }
            if (row < rlim) run += v;
        }
        if (run != 0.f)
            atomicAdd(&aggsum[(size_t)cur * H + jc], run * sinv[rend - 1]);
    }

    // fused e'-stats
    {
        float a = s1, b = s2;
        a += __shfl_xor(a, 16); a += __shfl_xor(a, 32);
        b += __shfl_xor(b, 16); b += __shfl_xor(b, 32);
        if (g == 0) {
            atomicAdd(&eStats[j], a);
            atomicAdd(&eStats[H + j], b);
        }
    }
}

// ---------------------------------------------------------------------------
// Node update, 512 threads: h = relu(bn_h(h)@V1 + aggmean@V2 + b2);
// fused h-stats; zeroes its aggsum rows.
__global__ __launch_bounds__(512, 4) void node_kernel(unsigned short* hb,
                                                      float* __restrict__ aggsum,
                                                      const short8* __restrict__ wfrL,
                                                      const float* __restrict__ b2, int M,
                                                      const float* __restrict__ Sh,
                                                      const float* __restrict__ gh,
                                                      const float* __restrict__ bh,
                                                      float invN,
                                                      float* __restrict__ hStats)
{
    __shared__ __align__(16) unsigned short sA[64 * 128];
    __shared__ __align__(16) unsigned short sB[64 * 128];
    __shared__ float bnp[256];
    const int t = threadIdx.x, lane = t & 63, w = t >> 6;
    const int r0 = blockIdx.x * 64;
    const int g = lane >> 4, c0 = lane & 15;
    const int j = 16 * w + c0;
    if (t < 128) bn_param(Sh, gh, bh, invN, t, bnp, bnp + 128);
    __syncthreads();
    stage_aff(hb, sA, r0, M, t, bnp, bnp + 128);
    stage_agg_bf16(aggsum, sB, r0, M, t);   // also zeroes consumed rows
    short8 wf[4];
    f32x4 acc[4];
    zero_acc_h(acc);
    load_wfrag_h(wfrL + 5 * 2048, w, lane, wf);   // V1
    __syncthreads();
    mfma_gemm_h(sA, wf, acc, lane);
    load_wfrag_h(wfrL + 6 * 2048, w, lane, wf);   // V2
    mfma_gemm_h(sB, wf, acc, lane);
    float s1 = 0.f, s2 = 0.f;
    {
        float bj = b2[j];
#pragma unroll
        for (int fr = 0; fr < 4; ++fr)
#pragma unroll
            for (int r = 0; r < 4; ++r) {
                int row = r0 + 16 * fr + 4 * g + r;
                if (row < M) {
                    float v = fmaxf(acc[fr][r] + bj, 0.f);
                    hb[(size_t)row * H + j] = f2bf(v);
                    s1 += v;
                    s2 += v * v;
                }
            }
    }
    {
        float a = s1, b = s2;
        a += __shfl_xor(a, 16); a += __shfl_xor(a, 32);
        b += __shfl_xor(b, 16); b += __shfl_xor(b, 32);
        if (g == 0) {
            atomicAdd(&hStats[j], a);
            atomicAdd(&hStats[H + j], b);
        }
    }
}

// ---------------------------------------------------------------------------
// Final readout: out = [mean(h) | mean(e)] @ reg_w + reg_b
__global__ __launch_bounds__(256) void final_kernel(const float* __restrict__ hsum,
                                                    const float* __restrict__ esum,
                                                    const float* __restrict__ reg_w,
                                                    const float* __restrict__ reg_b,
                                                    float* __restrict__ out,
                                                    float invN, float invE)
{
    __shared__ float red[256];
    int t = threadIdx.x;
    float v = (t < 128) ? hsum[t] * invN * reg_w[t]
                        : esum[t - 128] * invE * reg_w[t];
    red[t] = v;
    __syncthreads();
    for (int s = 128; s > 0; s >>= 1) {
        if (t < s) red[t] += red[t + s];
        __syncthreads();
    }
    if (t == 0) out[0] = red[0] + reg_b[0];
}

// ---------------------------------------------------------------------------
extern "C" void kernel_launch(void* const* d_in, const int* in_sizes, int n_in,
                              void* d_out, int out_size, void* d_ws, size_t ws_size,
                              hipStream_t stream)
{
    const float* x          = (const float*)d_in[0];
    const int*   edge_index = (const int*)  d_in[1];
    const float* edge_attr  = (const float*)d_in[2];
    const float* enc_node_w = (const float*)d_in[3];
    const float* enc_node_b = (const float*)d_in[4];
    const float* enc_edge_w = (const float*)d_in[5];
    const float* enc_edge_b = (const float*)d_in[6];
    const float* edge_w     = (const float*)d_in[7];
    const float* edge_b     = (const float*)d_in[8];
    const float* n1_w       = (const float*)d_in[9];
    const float* n1_b       = (const float*)d_in[10];
    const float* n2_w       = (const float*)d_in[11];
    const float* n2_b       = (const float*)d_in[12];
    const float* bn_node_g  = (const float*)d_in[13];
    const float* bn_node_b  = (const float*)d_in[14];
    const float* bn_edge_g  = (const float*)d_in[15];
    const float* bn_edge_b  = (const float*)d_in[16];
    const float* reg_w      = (const float*)d_in[17];
    const float* reg_b      = (const float*)d_in[18];

    const int N = in_sizes[0] / F_IN;
    const int E = in_sizes[1] / 2;
    const size_t NH = (size_t)N * H;
    const size_t EH = (size_t)E * H;

    float* ws     = (float*)d_ws;
    float* aggsum = ws;                 // [N,128] f32 (zeroed once; node re-zeroes)
    float* statsA = aggsum + NH;        // 512
    float* statsB = statsA + 512;       // 512
    short8* wfr   = (short8*)(statsB + 512);        // 21*2048 short8 = 672 KB
    unsigned short* hbuf = (unsigned short*)(wfr + 21 * 2048);  // [N,128] bf16
    unsigned short* ebuf = hbuf + NH;                           // [E,128] bf16 (col-sorted)
    int*   cnt_i  = (int*)(ebuf + EH);      // [N]
    int*   tmpc   = cnt_i + N;              // [N]
    int*   offs   = tmpc + N;               // [N+1]
    int*   sortedIds = offs + N + 1;        // [E]
    int*   rowS   = sortedIds + E;          // [E]
    int*   colS   = rowS + E;               // [E]

    const int* row_idx = edge_index;
    const int* col_idx = edge_index + E;
    const float invN = 1.f / (float)N;
    const float invE = 1.f / (float)E;

    // one-time: sort edges by col; bf16 weight fragments; encoders
    (void)hipMemsetAsync(cnt_i, 0, (size_t)2 * N * sizeof(int), stream);
    (void)hipMemsetAsync(aggsum, 0, NH * sizeof(float), stream);
    hist_kernel<<<(E + 255) / 256, 256, 0, stream>>>(col_idx, cnt_i, E);
    scan_kernel<<<1, 1024, 0, stream>>>(cnt_i, offs, N);
    scatter_kernel<<<(E + 255) / 256, 256, 0, stream>>>(row_idx, col_idx, offs, tmpc,
                                                        sortedIds, rowS, colS, E);
    wbf16_kernel<<<21, 256, 0, stream>>>(edge_w, n1_w, n2_w, wfr);

    enc_kernel<<<(N + 1) / 2, 256, 0, stream>>>(x, enc_node_w, enc_node_b, hbuf, N);
    enc_gather_kernel<<<(E + 1) / 2, 256, 0, stream>>>(edge_attr, sortedIds,
                                                       enc_edge_w, enc_edge_b, ebuf, E);

    const int nodeBlocks = (N + 63) / 64;
    const int edgeBlocks = (E + 63) / 64;

    for (int i = 0; i < 3; ++i) {
        float*       Scur  = (i & 1) ? statsB : statsA;
        const float* Sprev = (i == 0) ? nullptr : ((i & 1) ? statsA : statsB);
        const float* Sh = Sprev;
        const float* Se = Sprev ? Sprev + 256 : nullptr;
        const short8* wfrL = wfr + (size_t)i * 7 * 2048;
        (void)hipMemsetAsync(Scur, 0, 512 * sizeof(float), stream);
        edge_kernel<<<edgeBlocks, 512, 0, stream>>>(
            ebuf, rowS, colS, cnt_i, hbuf, wfrL,
            edge_b + i * H, n1_b + i * H,
            aggsum, E,
            Sh, bn_node_g, bn_node_b, invN,
            Se, bn_edge_g, bn_edge_b, invE,
            Scur + 256);
        node_kernel<<<nodeBlocks, 512, 0, stream>>>(
            hbuf, aggsum, wfrL, n2_b + i * H, N,
            Sh, bn_node_g, bn_node_b, invN,
            Scur);
    }
    // i=2 wrote statsA
    final_kernel<<<1, 256, 0, stream>>>(statsA, statsA + 256, reg_w, reg_b,
                                        (float*)d_out, invN, invE);
}